// Round 2
// baseline (1004.266 us; speedup 1.0000x reference)
//
#include <hip/hip_runtime.h>
#include <math.h>

#define DIMX 384
#define NHEAD 6
#define DHEAD 64
#define HW 3136   // 56*56
#define LKV 784   // 28*28
#define NGDX 128
#define NGRP 24   // B*3

// ---------------------------------------------------------------------------
// GEMM: out[b,o,p] = sum_c W[o,c] * in[b,c,p] (+ bias[o])
// grid: (ceil(P/64), O/64, B), block: 256
// ---------------------------------------------------------------------------
template<bool BIAS>
__global__ __launch_bounds__(256) void gemm_cw(
    const float* __restrict__ W, const float* __restrict__ in,
    const float* __restrict__ bias, float* __restrict__ out,
    int C, int P, int O)
{
  const int b  = blockIdx.z;
  const int o0 = blockIdx.y * 64;
  const int p0 = blockIdx.x * 64;
  __shared__ __align__(16) float At[32][68];  // At[cc][o]
  __shared__ __align__(16) float Bt[32][68];  // Bt[cc][p]
  const int tid = threadIdx.x;
  const int ty = tid >> 4, tx = tid & 15;
  float acc[4][4] = {};
  const float* inb = in + (size_t)b * C * P;

  for (int c0 = 0; c0 < C; c0 += 32) {
    // A tile: W[o0+o][c0+cc] -> At[cc][o]
#pragma unroll
    for (int it = 0; it < 2; ++it) {
      int e  = (tid + it * 256) * 4;     // element in 64x32 tile
      int o  = e >> 5, cc = e & 31;
      const float4 v = *(const float4*)(W + (size_t)(o0 + o) * C + c0 + cc);
      At[cc + 0][o] = v.x; At[cc + 1][o] = v.y;
      At[cc + 2][o] = v.z; At[cc + 3][o] = v.w;
    }
    // B tile: in[c0+cc][p0+pp] -> Bt[cc][pp]
#pragma unroll
    for (int it = 0; it < 2; ++it) {
      int e  = (tid + it * 256) * 4;     // element in 32x64 tile
      int cc = e >> 6, pp = e & 63;
      int p  = p0 + pp;
      float4 v;
      if (p + 3 < P) {
        v = *(const float4*)(inb + (size_t)(c0 + cc) * P + p);
      } else {
        const float* r = inb + (size_t)(c0 + cc) * P;
        v.x = (p + 0 < P) ? r[p + 0] : 0.f;
        v.y = (p + 1 < P) ? r[p + 1] : 0.f;
        v.z = (p + 2 < P) ? r[p + 2] : 0.f;
        v.w = (p + 3 < P) ? r[p + 3] : 0.f;
      }
      *(float4*)&Bt[cc][pp] = v;
    }
    __syncthreads();
#pragma unroll
    for (int cc = 0; cc < 32; ++cc) {
      const float4 a4 = *(const float4*)&At[cc][ty * 4];
      const float4 b4 = *(const float4*)&Bt[cc][tx * 4];
      const float a[4]  = {a4.x, a4.y, a4.z, a4.w};
      const float bb[4] = {b4.x, b4.y, b4.z, b4.w};
#pragma unroll
      for (int i = 0; i < 4; ++i)
#pragma unroll
        for (int j = 0; j < 4; ++j)
          acc[i][j] += a[i] * bb[j];
    }
    __syncthreads();
  }

#pragma unroll
  for (int i = 0; i < 4; ++i) {
    const int o = o0 + ty * 4 + i;
    float* orow = out + ((size_t)b * O + o) * P;
    const float bi = BIAS ? bias[o] : 0.f;
    const int p = p0 + tx * 4;
    if (p + 3 < P) {
      float4 v = {acc[i][0] + bi, acc[i][1] + bi, acc[i][2] + bi, acc[i][3] + bi};
      *(float4*)(orow + p) = v;
    } else {
#pragma unroll
      for (int j = 0; j < 4; ++j)
        if (p + j < P) orow[p + j] = acc[i][j] + bi;
    }
  }
}

// ---------------------------------------------------------------------------
// Depthwise 5x5 stride-2 conv + bias + BN + exact GELU
// q viewed as (24,128,56,56) -> off (24,128,28,28)
// grid: 3072 (=24*128), block: 256
// ---------------------------------------------------------------------------
__global__ __launch_bounds__(256) void dw_bn_gelu(
    const float* __restrict__ q, const float* __restrict__ dw_w,
    const float* __restrict__ dw_b, const float* __restrict__ bn_w,
    const float* __restrict__ bn_b, const float* __restrict__ bn_mean,
    const float* __restrict__ bn_var, float* __restrict__ off)
{
  const int nc = blockIdx.x;          // 0..3071
  const int c  = nc & 127;
  const float* plane = q + (size_t)nc * HW;
  float w[25];
#pragma unroll
  for (int k = 0; k < 25; ++k) w[k] = dw_w[c * 25 + k];
  const float beta  = dw_b[c];
  const float scale = bn_w[c] * rsqrtf(bn_var[c] + 1e-6f);
  const float shift = bn_b[c] - bn_mean[c] * scale;

  for (int p = threadIdx.x; p < LKV; p += 256) {
    const int oy = p / 28, ox = p % 28;
    const int iy0 = oy * 2 - 2, ix0 = ox * 2 - 2;
    float s = 0.f;
#pragma unroll
    for (int ky = 0; ky < 5; ++ky) {
      const int y = iy0 + ky;
      if ((unsigned)y >= 56u) continue;
#pragma unroll
      for (int kx = 0; kx < 5; ++kx) {
        const int x = ix0 + kx;
        if ((unsigned)x >= 56u) continue;
        s += plane[y * 56 + x] * w[ky * 5 + kx];
      }
    }
    s = (s + beta) * scale + shift;
    const float g = 0.5f * s * (1.f + erff(s * 0.70710678118654752f));
    off[(size_t)nc * LKV + p] = g;
  }
}

// ---------------------------------------------------------------------------
// Pointwise (3,128) over off -> offsets/modulation -> sampling coords
// NOTE: reference applies sigmoid TWICE to the modulation channel:
//   modulation = sigmoid(om[:,2]); x_s *= sigmoid(modulation)
// grid: (4, 24), block: 256
// ---------------------------------------------------------------------------
__global__ __launch_bounds__(256) void om_grid(
    const float* __restrict__ off, const float* __restrict__ pw_w,
    float* __restrict__ gxy, float* __restrict__ modb)
{
  const int n = blockIdx.y;
  const int p = blockIdx.x * 256 + threadIdx.x;
  if (p >= LKV) return;
  const float* base = off + (size_t)n * NGDX * LKV + p;
  float s0 = 0.f, s1 = 0.f, s2 = 0.f;
  for (int c = 0; c < NGDX; ++c) {
    const float v = base[(size_t)c * LKV];
    s0 += v * pw_w[c];
    s1 += v * pw_w[128 + c];
    s2 += v * pw_w[256 + c];
  }
  const float sig1 = 1.f / (1.f + expf(-s2));
  const float mod  = 1.f / (1.f + expf(-sig1));   // double sigmoid (per reference)
  const float offy = tanhf(s0) * (2.f / 28.f);
  const float offx = tanhf(s1) * (2.f / 28.f);
  const int i = p / 28, j = p % 28;
  const float refy = ((i + 0.5f) / 28.f) * 2.f - 1.f;
  const float refx = ((j + 0.5f) / 28.f) * 2.f - 1.f;
  const float gy = (offy + refy + 1.f) * 0.5f * 55.f;
  const float gx = (offx + refx + 1.f) * 0.5f * 55.f;
  gxy[((size_t)n * LKV + p) * 2 + 0] = gx;
  gxy[((size_t)n * LKV + p) * 2 + 1] = gy;
  modb[(size_t)n * LKV + p] = mod;
}

// ---------------------------------------------------------------------------
// Bilinear sample of x (24,128,56,56) at gxy, times modulation -> xs (24,128,784)
// grid: 3072 (=24*128), block: 256
// ---------------------------------------------------------------------------
__global__ __launch_bounds__(256) void sample_mod(
    const float* __restrict__ x, const float* __restrict__ gxy,
    const float* __restrict__ modb, float* __restrict__ xs)
{
  const int nc = blockIdx.x;
  const int n  = nc >> 7;
  const float* img = x + (size_t)nc * HW;
  for (int p = threadIdx.x; p < LKV; p += 256) {
    const float gx = gxy[((size_t)n * LKV + p) * 2 + 0];
    const float gy = gxy[((size_t)n * LKV + p) * 2 + 1];
    const float x0f = floorf(gx), y0f = floorf(gy);
    const float wx1 = gx - x0f, wy1 = gy - y0f;
    const float wx0 = (x0f + 1.f) - gx, wy0 = (y0f + 1.f) - gy;
    const int ix0 = (int)x0f, iy0 = (int)y0f;
    const int ix1 = ix0 + 1,  iy1 = iy0 + 1;
    const bool vx0 = (ix0 >= 0) && (ix0 < 56), vx1 = (ix1 >= 0) && (ix1 < 56);
    const bool vy0 = (iy0 >= 0) && (iy0 < 56), vy1 = (iy1 >= 0) && (iy1 < 56);
    const int cx0 = min(max(ix0, 0), 55), cx1 = min(max(ix1, 0), 55);
    const int cy0 = min(max(iy0, 0), 55), cy1 = min(max(iy1, 0), 55);
    const float f00 = (vy0 && vx0) ? img[cy0 * 56 + cx0] : 0.f;
    const float f10 = (vy1 && vx0) ? img[cy1 * 56 + cx0] : 0.f;
    const float f01 = (vy0 && vx1) ? img[cy0 * 56 + cx1] : 0.f;
    const float f11 = (vy1 && vx1) ? img[cy1 * 56 + cx1] : 0.f;
    const float v = f00 * (wx0 * wy0) + f10 * (wx0 * wy1)
                  + f01 * (wx1 * wy0) + f11 * (wx1 * wy1);
    xs[(size_t)nc * LKV + p] = v * modb[(size_t)n * LKV + p];
  }
}

// ---------------------------------------------------------------------------
// Fused flash attention. Q tile = 64 rows. K/V streamed in 64-key tiles.
// q:(8,384,3136) kv:(8,768,784) ao:(8,384,3136)
// grid: (49, 6, 8), block 256 (16x16 threads, 4x4 register tiles)
// ---------------------------------------------------------------------------
__device__ inline float4 load4_guard(const float* row, int idx, int n) {
  float4 v;
  if (idx + 3 < n) {
    v = *(const float4*)(row + idx);
  } else {
    v.x = (idx + 0 < n) ? row[idx + 0] : 0.f;
    v.y = (idx + 1 < n) ? row[idx + 1] : 0.f;
    v.z = (idx + 2 < n) ? row[idx + 2] : 0.f;
    v.w = (idx + 3 < n) ? row[idx + 3] : 0.f;
  }
  return v;
}

__global__ __launch_bounds__(256) void attn_fused(
    const float* __restrict__ q, const float* __restrict__ kv,
    float* __restrict__ ao)
{
  const int p0 = blockIdx.x * 64;
  const int h  = blockIdx.y;
  const int b  = blockIdx.z;
  __shared__ __align__(16) float Qs[64][68];  // [d][r], pre-scaled
  __shared__ __align__(16) float Kt[64][68];  // [d][l]
  __shared__ __align__(16) float Vt[64][68];  // [l][d]
  __shared__ __align__(16) float Ps[64][68];  // [l][r]
  const int tid = threadIdx.x;
  const int ty = tid >> 4, tx = tid & 15;
  const float* qb = q  + ((size_t)b * DIMX + h * DHEAD) * HW;
  const float* kb = kv + ((size_t)b * 2 * DIMX + h * DHEAD) * LKV;
  const float* vb = kv + ((size_t)b * 2 * DIMX + DIMX + h * DHEAD) * LKV;

  // stage Q (x SCALE)
#pragma unroll
  for (int it = 0; it < 4; ++it) {
    const int e = (tid + it * 256) * 4;
    const int d = e >> 6, r = e & 63;
    float4 v = *(const float4*)(qb + (size_t)d * HW + p0 + r);
    v.x *= 0.125f; v.y *= 0.125f; v.z *= 0.125f; v.w *= 0.125f;
    *(float4*)&Qs[d][r] = v;
  }
  float m_r[4], l_r[4];
#pragma unroll
  for (int i = 0; i < 4; ++i) { m_r[i] = -1e30f; l_r[i] = 0.f; }
  float acc[4][4] = {};
  __syncthreads();

  for (int kt = 0; kt < 13; ++kt) {
    const int l0 = kt * 64;
    // stage K -> Kt[d][l], V -> Vt[l][d]
#pragma unroll
    for (int it = 0; it < 4; ++it) {
      const int e = (tid + it * 256) * 4;
      const int d = e >> 6, l = e & 63;
      const float4 kk = load4_guard(kb + (size_t)d * LKV, l0 + l, LKV);
      *(float4*)&Kt[d][l] = kk;
      const float4 vv = load4_guard(vb + (size_t)d * LKV, l0 + l, LKV);
      Vt[l + 0][d] = vv.x; Vt[l + 1][d] = vv.y;
      Vt[l + 2][d] = vv.z; Vt[l + 3][d] = vv.w;
    }
    __syncthreads();

    // scores s[i][j] = sum_d Qs[d][ty*4+i] * Kt[d][tx*4+j]
    float s[4][4] = {};
#pragma unroll
    for (int d = 0; d < 64; ++d) {
      const float4 a4 = *(const float4*)&Qs[d][ty * 4];
      const float4 b4 = *(const float4*)&Kt[d][tx * 4];
      const float a[4]  = {a4.x, a4.y, a4.z, a4.w};
      const float bb[4] = {b4.x, b4.y, b4.z, b4.w};
#pragma unroll
      for (int i = 0; i < 4; ++i)
#pragma unroll
        for (int j = 0; j < 4; ++j)
          s[i][j] += a[i] * bb[j];
    }
    if (l0 + 63 >= LKV) {
#pragma unroll
      for (int j = 0; j < 4; ++j)
        if (l0 + tx * 4 + j >= LKV) {
#pragma unroll
          for (int i = 0; i < 4; ++i) s[i][j] = -1e30f;
        }
    }

    // online softmax (all 16 lanes of a row are in the same wave)
#pragma unroll
    for (int i = 0; i < 4; ++i) {
      float tm = fmaxf(fmaxf(s[i][0], s[i][1]), fmaxf(s[i][2], s[i][3]));
      tm = fmaxf(tm, __shfl_xor(tm, 1));
      tm = fmaxf(tm, __shfl_xor(tm, 2));
      tm = fmaxf(tm, __shfl_xor(tm, 4));
      tm = fmaxf(tm, __shfl_xor(tm, 8));
      const float mn = fmaxf(m_r[i], tm);
      const float sc = expf(m_r[i] - mn);
      m_r[i] = mn;
      l_r[i] *= sc;
      float ps = 0.f;
#pragma unroll
      for (int j = 0; j < 4; ++j) {
        const float pv = expf(s[i][j] - mn);
        s[i][j] = pv;
        ps += pv;
      }
      ps += __shfl_xor(ps, 1);
      ps += __shfl_xor(ps, 2);
      ps += __shfl_xor(ps, 4);
      ps += __shfl_xor(ps, 8);
      l_r[i] += ps;
#pragma unroll
      for (int j = 0; j < 4; ++j) acc[i][j] *= sc;
    }

    // P -> Ps[l][r]
#pragma unroll
    for (int i = 0; i < 4; ++i)
#pragma unroll
      for (int j = 0; j < 4; ++j)
        Ps[tx * 4 + j][ty * 4 + i] = s[i][j];
    __syncthreads();

    // acc[i][j] += sum_l Ps[l][ty*4+i] * Vt[l][tx*4+j]
#pragma unroll
    for (int l = 0; l < 64; ++l) {
      const float4 p4 = *(const float4*)&Ps[l][ty * 4];
      const float4 v4 = *(const float4*)&Vt[l][tx * 4];
      const float pp[4] = {p4.x, p4.y, p4.z, p4.w};
      const float vv[4] = {v4.x, v4.y, v4.z, v4.w};
#pragma unroll
      for (int i = 0; i < 4; ++i)
#pragma unroll
        for (int j = 0; j < 4; ++j)
          acc[i][j] += pp[i] * vv[j];
    }
    __syncthreads();
  }

  // ao[(b*384 + h*64 + d)*HW + p], d = tx*4+j, p = p0 + ty*4 + i
#pragma unroll
  for (int j = 0; j < 4; ++j) {
    const float4 o4 = {acc[0][j] / l_r[0], acc[1][j] / l_r[1],
                       acc[2][j] / l_r[2], acc[3][j] / l_r[3]};
    *(float4*)(ao + ((size_t)b * DIMX + h * DHEAD + tx * 4 + j) * HW + p0 + ty * 4) = o4;
  }
}

// ---------------------------------------------------------------------------
extern "C" void kernel_launch(void* const* d_in, const int* in_sizes, int n_in,
                              void* d_out, int out_size, void* d_ws, size_t ws_size,
                              hipStream_t stream) {
  const float* x       = (const float*)d_in[0];
  const float* q_w     = (const float*)d_in[1];
  const float* kv_w    = (const float*)d_in[2];
  const float* proj_w  = (const float*)d_in[3];
  const float* proj_b  = (const float*)d_in[4];
  const float* dw_w    = (const float*)d_in[5];
  const float* dw_b    = (const float*)d_in[6];
  const float* bn_w    = (const float*)d_in[7];
  const float* bn_b    = (const float*)d_in[8];
  const float* bn_mean = (const float*)d_in[9];
  const float* bn_var  = (const float*)d_in[10];
  const float* pw_w    = (const float*)d_in[11];
  float* out = (float*)d_out;

  // workspace layout (floats): total 19,324,032 f = 77.3 MB
  float* ws   = (float*)d_ws;
  float* qbuf = ws;                       // 9,633,792  (8,384,3136)
  float* kvb  = qbuf + 9633792;           // 4,816,896  (8,768,784)
  float* offb = kvb + 4816896;            // 2,408,448  (24,128,784)
  float* gxy  = offb + 2408448;           //    37,632  (24,784,2)
  float* modb = gxy + 37632;              //    18,816  (24,784)
  float* xsb  = modb + 18816;             // 2,408,448  (24,128,784)

  const dim3 blk(256);
  // 1. q projection
  gemm_cw<false><<<dim3(49, 6, 8), blk, 0, stream>>>(q_w, x, nullptr, qbuf, 384, 3136, 384);
  // 2. depthwise conv + BN + GELU
  dw_bn_gelu<<<dim3(3072), blk, 0, stream>>>(qbuf, dw_w, dw_b, bn_w, bn_b, bn_mean, bn_var, offb);
  // 3. pointwise -> offsets + modulation -> sample coords
  om_grid<<<dim3(4, 24), blk, 0, stream>>>(offb, pw_w, gxy, modb);
  // 4. bilinear sample * sigmoid(sigmoid(mod))
  sample_mod<<<dim3(3072), blk, 0, stream>>>(x, gxy, modb, xsb);
  // 5. kv projection
  gemm_cw<false><<<dim3(13, 12, 8), blk, 0, stream>>>(kv_w, xsb, nullptr, kvb, 384, 784, 768);
  // 6. fused attention -> d_out (staging)
  attn_fused<<<dim3(49, 6, 8), blk, 0, stream>>>(qbuf, kvb, out);
  // 7. out projection: reads d_out, writes qbuf (dead), then copy back
  gemm_cw<true><<<dim3(49, 6, 8), blk, 0, stream>>>(proj_w, out, proj_b, qbuf, 384, 3136, 384);
  hipMemcpyAsync(out, qbuf, (size_t)9633792 * sizeof(float), hipMemcpyDeviceToDevice, stream);
}

// Round 3
// 531.739 us; speedup vs baseline: 1.8886x; 1.8886x over previous
//
#include <hip/hip_runtime.h>
#include <math.h>

#define DIMX 384
#define NHEAD 6
#define DHEAD 64
#define HW 3136   // 56*56
#define LKV 784   // 28*28
#define NGDX 128
#define NGRP 24   // B*3

typedef __bf16 bf16_t;
typedef __bf16 bf16x4 __attribute__((ext_vector_type(4)));
typedef __bf16 bf16x8 __attribute__((ext_vector_type(8)));
typedef float  f32x4  __attribute__((ext_vector_type(4)));

static __device__ __forceinline__ f32x4 mfma16(bf16x8 a, bf16x8 b, f32x4 c) {
  return __builtin_amdgcn_mfma_f32_16x16x32_bf16(a, b, c, 0, 0, 0);
}

// ---------------------------------------------------------------------------
// GEMM: out[b,o,p] = sum_c W[o,c] * in[b,c,p] (+ bias[o])   (fp32, unchanged)
// ---------------------------------------------------------------------------
template<bool BIAS>
__global__ __launch_bounds__(256) void gemm_cw(
    const float* __restrict__ W, const float* __restrict__ in,
    const float* __restrict__ bias, float* __restrict__ out,
    int C, int P, int O)
{
  const int b  = blockIdx.z;
  const int o0 = blockIdx.y * 64;
  const int p0 = blockIdx.x * 64;
  __shared__ __align__(16) float At[32][68];
  __shared__ __align__(16) float Bt[32][68];
  const int tid = threadIdx.x;
  const int ty = tid >> 4, tx = tid & 15;
  float acc[4][4] = {};
  const float* inb = in + (size_t)b * C * P;

  for (int c0 = 0; c0 < C; c0 += 32) {
#pragma unroll
    for (int it = 0; it < 2; ++it) {
      int e  = (tid + it * 256) * 4;
      int o  = e >> 5, cc = e & 31;
      const float4 v = *(const float4*)(W + (size_t)(o0 + o) * C + c0 + cc);
      At[cc + 0][o] = v.x; At[cc + 1][o] = v.y;
      At[cc + 2][o] = v.z; At[cc + 3][o] = v.w;
    }
#pragma unroll
    for (int it = 0; it < 2; ++it) {
      int e  = (tid + it * 256) * 4;
      int cc = e >> 6, pp = e & 63;
      int p  = p0 + pp;
      float4 v;
      if (p + 3 < P) {
        v = *(const float4*)(inb + (size_t)(c0 + cc) * P + p);
      } else {
        const float* r = inb + (size_t)(c0 + cc) * P;
        v.x = (p + 0 < P) ? r[p + 0] : 0.f;
        v.y = (p + 1 < P) ? r[p + 1] : 0.f;
        v.z = (p + 2 < P) ? r[p + 2] : 0.f;
        v.w = (p + 3 < P) ? r[p + 3] : 0.f;
      }
      *(float4*)&Bt[cc][pp] = v;
    }
    __syncthreads();
#pragma unroll
    for (int cc = 0; cc < 32; ++cc) {
      const float4 a4 = *(const float4*)&At[cc][ty * 4];
      const float4 b4 = *(const float4*)&Bt[cc][tx * 4];
      const float a[4]  = {a4.x, a4.y, a4.z, a4.w};
      const float bb[4] = {b4.x, b4.y, b4.z, b4.w};
#pragma unroll
      for (int i = 0; i < 4; ++i)
#pragma unroll
        for (int j = 0; j < 4; ++j)
          acc[i][j] += a[i] * bb[j];
    }
    __syncthreads();
  }

#pragma unroll
  for (int i = 0; i < 4; ++i) {
    const int o = o0 + ty * 4 + i;
    float* orow = out + ((size_t)b * O + o) * P;
    const float bi = BIAS ? bias[o] : 0.f;
    const int p = p0 + tx * 4;
    if (p + 3 < P) {
      float4 v = {acc[i][0] + bi, acc[i][1] + bi, acc[i][2] + bi, acc[i][3] + bi};
      *(float4*)(orow + p) = v;
    } else {
#pragma unroll
      for (int j = 0; j < 4; ++j)
        if (p + j < P) orow[p + j] = acc[i][j] + bi;
    }
  }
}

// ---------------------------------------------------------------------------
// Depthwise 5x5 stride-2 conv + bias + BN + exact GELU (unchanged)
// ---------------------------------------------------------------------------
__global__ __launch_bounds__(256) void dw_bn_gelu(
    const float* __restrict__ q, const float* __restrict__ dw_w,
    const float* __restrict__ dw_b, const float* __restrict__ bn_w,
    const float* __restrict__ bn_b, const float* __restrict__ bn_mean,
    const float* __restrict__ bn_var, float* __restrict__ off)
{
  const int nc = blockIdx.x;
  const int c  = nc & 127;
  const float* plane = q + (size_t)nc * HW;
  float w[25];
#pragma unroll
  for (int k = 0; k < 25; ++k) w[k] = dw_w[c * 25 + k];
  const float beta  = dw_b[c];
  const float scale = bn_w[c] * rsqrtf(bn_var[c] + 1e-6f);
  const float shift = bn_b[c] - bn_mean[c] * scale;

  for (int p = threadIdx.x; p < LKV; p += 256) {
    const int oy = p / 28, ox = p % 28;
    const int iy0 = oy * 2 - 2, ix0 = ox * 2 - 2;
    float s = 0.f;
#pragma unroll
    for (int ky = 0; ky < 5; ++ky) {
      const int y = iy0 + ky;
      if ((unsigned)y >= 56u) continue;
#pragma unroll
      for (int kx = 0; kx < 5; ++kx) {
        const int x = ix0 + kx;
        if ((unsigned)x >= 56u) continue;
        s += plane[y * 56 + x] * w[ky * 5 + kx];
      }
    }
    s = (s + beta) * scale + shift;
    const float g = 0.5f * s * (1.f + erff(s * 0.70710678118654752f));
    off[(size_t)nc * LKV + p] = g;
  }
}

// ---------------------------------------------------------------------------
// Pointwise (3,128) -> offsets/modulation -> sampling coords (unchanged;
// reference double-sigmoids the modulation channel)
// ---------------------------------------------------------------------------
__global__ __launch_bounds__(256) void om_grid(
    const float* __restrict__ off, const float* __restrict__ pw_w,
    float* __restrict__ gxy, float* __restrict__ modb)
{
  const int n = blockIdx.y;
  const int p = blockIdx.x * 256 + threadIdx.x;
  if (p >= LKV) return;
  const float* base = off + (size_t)n * NGDX * LKV + p;
  float s0 = 0.f, s1 = 0.f, s2 = 0.f;
  for (int c = 0; c < NGDX; ++c) {
    const float v = base[(size_t)c * LKV];
    s0 += v * pw_w[c];
    s1 += v * pw_w[128 + c];
    s2 += v * pw_w[256 + c];
  }
  const float sig1 = 1.f / (1.f + expf(-s2));
  const float mod  = 1.f / (1.f + expf(-sig1));   // double sigmoid (per reference)
  const float offy = tanhf(s0) * (2.f / 28.f);
  const float offx = tanhf(s1) * (2.f / 28.f);
  const int i = p / 28, j = p % 28;
  const float refy = ((i + 0.5f) / 28.f) * 2.f - 1.f;
  const float refx = ((j + 0.5f) / 28.f) * 2.f - 1.f;
  const float gy = (offy + refy + 1.f) * 0.5f * 55.f;
  const float gx = (offx + refx + 1.f) * 0.5f * 55.f;
  gxy[((size_t)n * LKV + p) * 2 + 0] = gx;
  gxy[((size_t)n * LKV + p) * 2 + 1] = gy;
  modb[(size_t)n * LKV + p] = mod;
}

// ---------------------------------------------------------------------------
// Bilinear sample * double-sigmoided modulation (unchanged)
// ---------------------------------------------------------------------------
__global__ __launch_bounds__(256) void sample_mod(
    const float* __restrict__ x, const float* __restrict__ gxy,
    const float* __restrict__ modb, float* __restrict__ xs)
{
  const int nc = blockIdx.x;
  const int n  = nc >> 7;
  const float* img = x + (size_t)nc * HW;
  for (int p = threadIdx.x; p < LKV; p += 256) {
    const float gx = gxy[((size_t)n * LKV + p) * 2 + 0];
    const float gy = gxy[((size_t)n * LKV + p) * 2 + 1];
    const float x0f = floorf(gx), y0f = floorf(gy);
    const float wx1 = gx - x0f, wy1 = gy - y0f;
    const float wx0 = (x0f + 1.f) - gx, wy0 = (y0f + 1.f) - gy;
    const int ix0 = (int)x0f, iy0 = (int)y0f;
    const int ix1 = ix0 + 1,  iy1 = iy0 + 1;
    const bool vx0 = (ix0 >= 0) && (ix0 < 56), vx1 = (ix1 >= 0) && (ix1 < 56);
    const bool vy0 = (iy0 >= 0) && (iy0 < 56), vy1 = (iy1 >= 0) && (iy1 < 56);
    const int cx0 = min(max(ix0, 0), 55), cx1 = min(max(ix1, 0), 55);
    const int cy0 = min(max(iy0, 0), 55), cy1 = min(max(iy1, 0), 55);
    const float f00 = (vy0 && vx0) ? img[cy0 * 56 + cx0] : 0.f;
    const float f10 = (vy1 && vx0) ? img[cy1 * 56 + cx0] : 0.f;
    const float f01 = (vy0 && vx1) ? img[cy0 * 56 + cx1] : 0.f;
    const float f11 = (vy1 && vx1) ? img[cy1 * 56 + cx1] : 0.f;
    const float v = f00 * (wx0 * wy0) + f10 * (wx0 * wy1)
                  + f01 * (wx1 * wy0) + f11 * (wx1 * wy1);
    xs[(size_t)nc * LKV + p] = v * modb[(size_t)n * LKV + p];
  }
}

// ---------------------------------------------------------------------------
// bf16 MFMA flash attention.
// grid (49,6,8), block 256 = 4 waves; each wave owns 16 q-rows.
// q,kv fp32 in channel-major layout: q[d][p] (p contig), k/v[d][l] (l contig).
// MFMA 16x16x32 layouts: A[lane&15][(lane>>4)*8+i], B[(lane>>4)*8+i][lane&15],
// D row=(lane>>4)*4+reg, col=lane&15.
// l padded 784 -> 13*64: zero-staged K/V + explicit -1e30 mask.
// ---------------------------------------------------------------------------
__global__ __launch_bounds__(256) void attn_mfma(
    const float* __restrict__ q, const float* __restrict__ kv,
    float* __restrict__ ao)
{
  const int p0 = blockIdx.x * 64;
  const int h  = blockIdx.y;
  const int b  = blockIdx.z;

  // LDS: Ks[64l][72] bf16 | Vs[64d][72] bf16 | Pl[64row][72] bf16
  // epilogue reuses bytes 0..17407 as Os[64d][68] f32
  __shared__ __align__(16) char smem[27648];
  bf16_t (*Ks)[72] = (bf16_t(*)[72])(smem);
  bf16_t (*Vs)[72] = (bf16_t(*)[72])(smem + 9216);
  bf16_t (*Pl)[72] = (bf16_t(*)[72])(smem + 18432);
  float  (*Os)[68] = (float (*)[68])(smem);

  const int tid  = threadIdx.x;
  const int w    = tid >> 6;
  const int lane = tid & 63;
  const int l15  = lane & 15;
  const int g    = lane >> 4;

  const float* qb = q  + (size_t)(b * DIMX + h * DHEAD) * HW;
  const float* kb = kv + (size_t)(b * 2 * DIMX + h * DHEAD) * LKV;
  const float* vb = kv + (size_t)(b * 2 * DIMX + DIMX + h * DHEAD) * LKV;

  // Q A-fragments in registers, pre-scaled by 1/8
  bf16x8 qf[2];
  {
    const int p = p0 + w * 16 + l15;
#pragma unroll
    for (int c = 0; c < 2; ++c)
#pragma unroll
      for (int i = 0; i < 8; ++i) {
        const int d = c * 32 + g * 8 + i;
        qf[c][i] = (bf16_t)(qb[(size_t)d * HW + p] * 0.125f);
      }
  }

  f32x4 acc[4];
  float m_r[4], l_r[4];
#pragma unroll
  for (int n = 0; n < 4; ++n) { acc[n][0] = 0.f; acc[n][1] = 0.f; acc[n][2] = 0.f; acc[n][3] = 0.f; }
#pragma unroll
  for (int r = 0; r < 4; ++r) { m_r[r] = -1e30f; l_r[r] = 0.f; }

  for (int t = 0; t < 13; ++t) {
    const int l0 = t * 64;
    // --- cooperative stage: K transposed -> Ks[l][d], V as-is -> Vs[d][l]
    {
      const int d  = tid >> 2;
      const int lo = (tid & 3) * 16;
#pragma unroll
      for (int j = 0; j < 4; ++j) {
        const int l  = lo + j * 4;
        const int lg = l0 + l;
        float4 kk, vv;
        if (lg < LKV) {
          kk = *(const float4*)(kb + (size_t)d * LKV + lg);
          vv = *(const float4*)(vb + (size_t)d * LKV + lg);
        } else {
          kk.x = kk.y = kk.z = kk.w = 0.f;
          vv.x = vv.y = vv.z = vv.w = 0.f;
        }
        Ks[l + 0][d] = (bf16_t)kk.x; Ks[l + 1][d] = (bf16_t)kk.y;
        Ks[l + 2][d] = (bf16_t)kk.z; Ks[l + 3][d] = (bf16_t)kk.w;
        bf16x4 pv;
        pv[0] = (bf16_t)vv.x; pv[1] = (bf16_t)vv.y;
        pv[2] = (bf16_t)vv.z; pv[3] = (bf16_t)vv.w;
        *(bf16x4*)&Vs[d][l] = pv;
      }
    }
    __syncthreads();

    // --- QK^T: S[16p][64l]
    f32x4 s[4];
#pragma unroll
    for (int n = 0; n < 4; ++n) {
      f32x4 z; z[0] = 0.f; z[1] = 0.f; z[2] = 0.f; z[3] = 0.f;
      const bf16x8 k0 = *(const bf16x8*)&Ks[n * 16 + l15][g * 8];
      const bf16x8 k1 = *(const bf16x8*)&Ks[n * 16 + l15][32 + g * 8];
      z = mfma16(qf[0], k0, z);
      z = mfma16(qf[1], k1, z);
      s[n] = z;
    }
    if (l0 + 64 > LKV) {
#pragma unroll
      for (int n = 0; n < 4; ++n)
        if (l0 + n * 16 + l15 >= LKV) {
#pragma unroll
          for (int r = 0; r < 4; ++r) s[n][r] = -1e30f;
        }
    }

    // --- online softmax (rows live across the 16-lane col group)
#pragma unroll
    for (int r = 0; r < 4; ++r) {
      float tm = fmaxf(fmaxf(s[0][r], s[1][r]), fmaxf(s[2][r], s[3][r]));
      tm = fmaxf(tm, __shfl_xor(tm, 1));
      tm = fmaxf(tm, __shfl_xor(tm, 2));
      tm = fmaxf(tm, __shfl_xor(tm, 4));
      tm = fmaxf(tm, __shfl_xor(tm, 8));
      const float mn = fmaxf(m_r[r], tm);
      const float sc = expf(m_r[r] - mn);
      m_r[r] = mn;
      l_r[r] *= sc;
      float ps = 0.f;
#pragma unroll
      for (int n = 0; n < 4; ++n) {
        const float pv = expf(s[n][r] - mn);
        s[n][r] = pv;
        ps += pv;
      }
      ps += __shfl_xor(ps, 1);
      ps += __shfl_xor(ps, 2);
      ps += __shfl_xor(ps, 4);
      ps += __shfl_xor(ps, 8);
      l_r[r] += ps;
#pragma unroll
      for (int n = 0; n < 4; ++n) acc[n][r] *= sc;
    }

    // --- P (bf16) -> per-wave LDS tile (wave-local: no barrier needed)
#pragma unroll
    for (int n = 0; n < 4; ++n)
#pragma unroll
      for (int r = 0; r < 4; ++r)
        Pl[w * 16 + g * 4 + r][n * 16 + l15] = (bf16_t)s[n][r];

    // --- PV: acc[16p][64d] += P[16p][64l] * V^T[64l][64d]
#pragma unroll
    for (int c2 = 0; c2 < 2; ++c2) {
      const bf16x8 pf = *(const bf16x8*)&Pl[w * 16 + l15][c2 * 32 + g * 8];
#pragma unroll
      for (int n = 0; n < 4; ++n) {
        const bf16x8 vf = *(const bf16x8*)&Vs[n * 16 + l15][c2 * 32 + g * 8];
        acc[n] = mfma16(pf, vf, acc[n]);
      }
    }
    __syncthreads();
  }

  // --- epilogue: normalize, transpose through LDS, coalesced store
  float inv[4];
#pragma unroll
  for (int r = 0; r < 4; ++r) inv[r] = 1.f / l_r[r];
#pragma unroll
  for (int n = 0; n < 4; ++n)
#pragma unroll
    for (int r = 0; r < 4; ++r)
      Os[n * 16 + l15][w * 16 + g * 4 + r] = acc[n][r] * inv[r];
  __syncthreads();
  {
    const int d  = tid >> 2;
    const int po = (tid & 3) * 16;
    float* orow = ao + (size_t)(b * DIMX + h * DHEAD + d) * HW + p0;
#pragma unroll
    for (int j = 0; j < 4; ++j) {
      const float4 v = *(const float4*)&Os[d][po + j * 4];
      *(float4*)(orow + po + j * 4) = v;
    }
  }
}

// ---------------------------------------------------------------------------
extern "C" void kernel_launch(void* const* d_in, const int* in_sizes, int n_in,
                              void* d_out, int out_size, void* d_ws, size_t ws_size,
                              hipStream_t stream) {
  const float* x       = (const float*)d_in[0];
  const float* q_w     = (const float*)d_in[1];
  const float* kv_w    = (const float*)d_in[2];
  const float* proj_w  = (const float*)d_in[3];
  const float* proj_b  = (const float*)d_in[4];
  const float* dw_w    = (const float*)d_in[5];
  const float* dw_b    = (const float*)d_in[6];
  const float* bn_w    = (const float*)d_in[7];
  const float* bn_b    = (const float*)d_in[8];
  const float* bn_mean = (const float*)d_in[9];
  const float* bn_var  = (const float*)d_in[10];
  const float* pw_w    = (const float*)d_in[11];
  float* out = (float*)d_out;

  // workspace layout (floats): total 19,324,032 f = 77.3 MB
  float* ws   = (float*)d_ws;
  float* qbuf = ws;                       // 9,633,792  (8,384,3136)
  float* kvb  = qbuf + 9633792;           // 4,816,896  (8,768,784)
  float* offb = kvb + 4816896;            // 2,408,448  (24,128,784)
  float* gxy  = offb + 2408448;           //    37,632  (24,784,2)
  float* modb = gxy + 37632;              //    18,816  (24,784)
  float* xsb  = modb + 18816;             // 2,408,448  (24,128,784)

  const dim3 blk(256);
  gemm_cw<false><<<dim3(49, 6, 8), blk, 0, stream>>>(q_w, x, nullptr, qbuf, 384, 3136, 384);
  dw_bn_gelu<<<dim3(3072), blk, 0, stream>>>(qbuf, dw_w, dw_b, bn_w, bn_b, bn_mean, bn_var, offb);
  om_grid<<<dim3(4, 24), blk, 0, stream>>>(offb, pw_w, gxy, modb);
  sample_mod<<<dim3(3072), blk, 0, stream>>>(x, gxy, modb, xsb);
  gemm_cw<false><<<dim3(13, 12, 8), blk, 0, stream>>>(kv_w, xsb, nullptr, kvb, 384, 784, 768);
  attn_mfma<<<dim3(49, 6, 8), blk, 0, stream>>>(qbuf, kvb, out);
  gemm_cw<true><<<dim3(49, 6, 8), blk, 0, stream>>>(proj_w, out, proj_b, qbuf, 384, 3136, 384);
  hipMemcpyAsync(out, qbuf, (size_t)9633792 * sizeof(float), hipMemcpyDeviceToDevice, stream);
}

// Round 4
// 292.877 us; speedup vs baseline: 3.4290x; 1.8156x over previous
//
#include <hip/hip_runtime.h>
#include <math.h>

#define DIMX 384
#define NHEAD 6
#define DHEAD 64
#define HW 3136   // 56*56
#define LKV 784   // 28*28
#define NGDX 128
#define NGRP 24   // B*3

typedef __bf16 bf16_t;
typedef __bf16 bf16x4 __attribute__((ext_vector_type(4)));
typedef __bf16 bf16x8 __attribute__((ext_vector_type(8)));
typedef float  f32x4  __attribute__((ext_vector_type(4)));

static __device__ __forceinline__ f32x4 mfma16(bf16x8 a, bf16x8 b, f32x4 c) {
  return __builtin_amdgcn_mfma_f32_16x16x32_bf16(a, b, c, 0, 0, 0);
}

// ---------------------------------------------------------------------------
// fp32 -> bf16 convert (n multiple of 4)
// ---------------------------------------------------------------------------
__global__ __launch_bounds__(256) void cvt_bf16(
    const float* __restrict__ src, bf16_t* __restrict__ dst, int n4)
{
  const int i = blockIdx.x * 256 + threadIdx.x;
  if (i >= n4) return;
  const float4 v = *(const float4*)(src + (size_t)i * 4);
  bf16x4 o;
  o[0] = (bf16_t)v.x; o[1] = (bf16_t)v.y; o[2] = (bf16_t)v.z; o[3] = (bf16_t)v.w;
  *(bf16x4*)(dst + (size_t)i * 4) = o;
}

// convert the three weight matrices into one bf16 arena
__global__ __launch_bounds__(256) void cvt_w3(
    const float* __restrict__ qw, const float* __restrict__ kvw,
    const float* __restrict__ pw, bf16_t* __restrict__ dst)
{
  const int i = blockIdx.x * 256 + threadIdx.x;   // i*4 element offset
  if (i >= 147456) return;                        // 589824/4
  const int e = i * 4;
  const float* src;
  int off;
  if (e < 147456)      { src = qw;  off = e; }
  else if (e < 442368) { src = kvw; off = e - 147456; }
  else                 { src = pw;  off = e - 442368; }
  const float4 v = *(const float4*)(src + off);
  bf16x4 o;
  o[0] = (bf16_t)v.x; o[1] = (bf16_t)v.y; o[2] = (bf16_t)v.z; o[3] = (bf16_t)v.w;
  *(bf16x4*)(dst + e) = o;
}

// ---------------------------------------------------------------------------
// bf16 MFMA GEMM: out[b,o,p] = sum_c W[o,c]*in[b,c,p] (+bias)
// 64x64 tile, BK=64, 4 waves (each: 16 o-rows x 64 p-cols).
// grid (ceil(P/64), O/64, B), block 256. P tail handled (P multiple of 16).
// ---------------------------------------------------------------------------
template<bool BIAS, bool OBF16>
__global__ __launch_bounds__(256) void gemm_mfma(
    const bf16_t* __restrict__ W, const bf16_t* __restrict__ in,
    const float* __restrict__ bias, void* __restrict__ outv,
    int C, int P, int O)
{
  const int b  = blockIdx.z;
  const int o0 = blockIdx.y * 64;
  const int p0 = blockIdx.x * 64;
  __shared__ __align__(16) bf16_t As[64][72];   // [o][c]
  __shared__ __align__(16) bf16_t Bs[64][72];   // [p][c] (transposed stage)
  const int tid = threadIdx.x;
  const int w = tid >> 6, lane = tid & 63, l15 = lane & 15, g = lane >> 4;
  const bf16_t* inb = in + (size_t)b * C * P;

  f32x4 acc[4];
#pragma unroll
  for (int n = 0; n < 4; ++n) { acc[n][0]=0.f; acc[n][1]=0.f; acc[n][2]=0.f; acc[n][3]=0.f; }

  for (int c0 = 0; c0 < C; c0 += 64) {
    // A: W[o0+o][c0+cc..] -> As[o][cc..], vector copy
    {
      const int o = tid >> 2, cc = (tid & 3) * 16;
      const bf16_t* src = W + (size_t)(o0 + o) * C + c0 + cc;
      *(bf16x8*)&As[o][cc]     = *(const bf16x8*)src;
      *(bf16x8*)&As[o][cc + 8] = *(const bf16x8*)(src + 8);
    }
    // B: in[c0+c][p0+pp..] -> Bs[pp][c] (transpose scatter)
    {
      const int c = tid >> 2, pp = (tid & 3) * 16;
      const bf16_t* src = inb + (size_t)(c0 + c) * P + p0 + pp;
#pragma unroll
      for (int jj = 0; jj < 2; ++jj) {
        bf16x8 v;
        if (p0 + pp + jj * 8 + 8 <= P) v = *(const bf16x8*)(src + jj * 8);
        else {
#pragma unroll
          for (int k = 0; k < 8; ++k) v[k] = (bf16_t)0.f;
        }
#pragma unroll
        for (int k = 0; k < 8; ++k) Bs[pp + jj * 8 + k][c] = v[k];
      }
    }
    __syncthreads();
#pragma unroll
    for (int ks = 0; ks < 2; ++ks) {
      const bf16x8 af = *(const bf16x8*)&As[w * 16 + l15][ks * 32 + g * 8];
#pragma unroll
      for (int n = 0; n < 4; ++n) {
        const bf16x8 bfr = *(const bf16x8*)&Bs[n * 16 + l15][ks * 32 + g * 8];
        acc[n] = mfma16(af, bfr, acc[n]);
      }
    }
    __syncthreads();
  }

  float badd[4];
#pragma unroll
  for (int r = 0; r < 4; ++r) badd[r] = BIAS ? bias[o0 + w * 16 + g * 4 + r] : 0.f;

#pragma unroll
  for (int n = 0; n < 4; ++n) {
    const int p = p0 + n * 16 + l15;
    if (p < P) {
#pragma unroll
      for (int r = 0; r < 4; ++r) {
        const int o = o0 + w * 16 + g * 4 + r;
        const float v = acc[n][r] + badd[r];
        if (OBF16) ((bf16_t*)outv)[((size_t)b * O + o) * P + p] = (bf16_t)v;
        else       ((float*)outv)[((size_t)b * O + o) * P + p] = v;
      }
    }
  }
}

// ---------------------------------------------------------------------------
// Depthwise 5x5 stride-2 conv + bias + BN + exact GELU (fp32, unchanged)
// ---------------------------------------------------------------------------
__global__ __launch_bounds__(256) void dw_bn_gelu(
    const float* __restrict__ q, const float* __restrict__ dw_w,
    const float* __restrict__ dw_b, const float* __restrict__ bn_w,
    const float* __restrict__ bn_b, const float* __restrict__ bn_mean,
    const float* __restrict__ bn_var, float* __restrict__ off)
{
  const int nc = blockIdx.x;
  const int c  = nc & 127;
  const float* plane = q + (size_t)nc * HW;
  float w[25];
#pragma unroll
  for (int k = 0; k < 25; ++k) w[k] = dw_w[c * 25 + k];
  const float beta  = dw_b[c];
  const float scale = bn_w[c] * rsqrtf(bn_var[c] + 1e-6f);
  const float shift = bn_b[c] - bn_mean[c] * scale;

  for (int p = threadIdx.x; p < LKV; p += 256) {
    const int oy = p / 28, ox = p % 28;
    const int iy0 = oy * 2 - 2, ix0 = ox * 2 - 2;
    float s = 0.f;
#pragma unroll
    for (int ky = 0; ky < 5; ++ky) {
      const int y = iy0 + ky;
      if ((unsigned)y >= 56u) continue;
#pragma unroll
      for (int kx = 0; kx < 5; ++kx) {
        const int x = ix0 + kx;
        if ((unsigned)x >= 56u) continue;
        s += plane[y * 56 + x] * w[ky * 5 + kx];
      }
    }
    s = (s + beta) * scale + shift;
    const float g = 0.5f * s * (1.f + erff(s * 0.70710678118654752f));
    off[(size_t)nc * LKV + p] = g;
  }
}

// ---------------------------------------------------------------------------
// Pointwise (3,128) -> offsets / double-sigmoid modulation -> sample coords
// ---------------------------------------------------------------------------
__global__ __launch_bounds__(256) void om_grid(
    const float* __restrict__ off, const float* __restrict__ pw_w,
    float* __restrict__ gxy, float* __restrict__ modb)
{
  const int n = blockIdx.y;
  const int p = blockIdx.x * 256 + threadIdx.x;
  if (p >= LKV) return;
  const float* base = off + (size_t)n * NGDX * LKV + p;
  float s0 = 0.f, s1 = 0.f, s2 = 0.f;
  for (int c = 0; c < NGDX; ++c) {
    const float v = base[(size_t)c * LKV];
    s0 += v * pw_w[c];
    s1 += v * pw_w[128 + c];
    s2 += v * pw_w[256 + c];
  }
  const float sig1 = 1.f / (1.f + expf(-s2));
  const float mod  = 1.f / (1.f + expf(-sig1));   // double sigmoid (per reference)
  const float offy = tanhf(s0) * (2.f / 28.f);
  const float offx = tanhf(s1) * (2.f / 28.f);
  const int i = p / 28, j = p % 28;
  const float refy = ((i + 0.5f) / 28.f) * 2.f - 1.f;
  const float refx = ((j + 0.5f) / 28.f) * 2.f - 1.f;
  const float gy = (offy + refy + 1.f) * 0.5f * 55.f;
  const float gx = (offx + refx + 1.f) * 0.5f * 55.f;
  gxy[((size_t)n * LKV + p) * 2 + 0] = gx;
  gxy[((size_t)n * LKV + p) * 2 + 1] = gy;
  modb[(size_t)n * LKV + p] = mod;
}

// ---------------------------------------------------------------------------
// Bilinear sample * modulation -> bf16 (feeds kv GEMM)
// ---------------------------------------------------------------------------
__global__ __launch_bounds__(256) void sample_mod(
    const float* __restrict__ x, const float* __restrict__ gxy,
    const float* __restrict__ modb, bf16_t* __restrict__ xs)
{
  const int nc = blockIdx.x;
  const int n  = nc >> 7;
  const float* img = x + (size_t)nc * HW;
  for (int p = threadIdx.x; p < LKV; p += 256) {
    const float gx = gxy[((size_t)n * LKV + p) * 2 + 0];
    const float gy = gxy[((size_t)n * LKV + p) * 2 + 1];
    const float x0f = floorf(gx), y0f = floorf(gy);
    const float wx1 = gx - x0f, wy1 = gy - y0f;
    const float wx0 = (x0f + 1.f) - gx, wy0 = (y0f + 1.f) - gy;
    const int ix0 = (int)x0f, iy0 = (int)y0f;
    const int ix1 = ix0 + 1,  iy1 = iy0 + 1;
    const bool vx0 = (ix0 >= 0) && (ix0 < 56), vx1 = (ix1 >= 0) && (ix1 < 56);
    const bool vy0 = (iy0 >= 0) && (iy0 < 56), vy1 = (iy1 >= 0) && (iy1 < 56);
    const int cx0 = min(max(ix0, 0), 55), cx1 = min(max(ix1, 0), 55);
    const int cy0 = min(max(iy0, 0), 55), cy1 = min(max(iy1, 0), 55);
    const float f00 = (vy0 && vx0) ? img[cy0 * 56 + cx0] : 0.f;
    const float f10 = (vy1 && vx0) ? img[cy1 * 56 + cx0] : 0.f;
    const float f01 = (vy0 && vx1) ? img[cy0 * 56 + cx1] : 0.f;
    const float f11 = (vy1 && vx1) ? img[cy1 * 56 + cx1] : 0.f;
    const float v = f00 * (wx0 * wy0) + f10 * (wx0 * wy1)
                  + f01 * (wx1 * wy0) + f11 * (wx1 * wy1);
    xs[(size_t)nc * LKV + p] = (bf16_t)(v * modb[(size_t)n * LKV + p]);
  }
}

// ---------------------------------------------------------------------------
// bf16 MFMA flash attention. q fp32 (channel-major), kv bf16, out bf16.
// grid (49,6,8), block 256 = 4 waves; wave owns 16 q-rows.
// ---------------------------------------------------------------------------
__global__ __launch_bounds__(256) void attn_mfma(
    const float* __restrict__ q, const bf16_t* __restrict__ kv,
    bf16_t* __restrict__ ao)
{
  const int p0 = blockIdx.x * 64;
  const int h  = blockIdx.y;
  const int b  = blockIdx.z;

  __shared__ __align__(16) char smem[27648];
  bf16_t (*Ks)[72] = (bf16_t(*)[72])(smem);          // [l][d]
  bf16_t (*Vs)[72] = (bf16_t(*)[72])(smem + 9216);   // [d][l]
  bf16_t (*Pl)[72] = (bf16_t(*)[72])(smem + 18432);  // [row][l]
  float  (*Os)[68] = (float (*)[68])(smem);          // epilogue reuse

  const int tid  = threadIdx.x;
  const int w    = tid >> 6;
  const int lane = tid & 63;
  const int l15  = lane & 15;
  const int g    = lane >> 4;

  const float*  qb = q  + (size_t)(b * DIMX + h * DHEAD) * HW;
  const bf16_t* kb = kv + (size_t)(b * 2 * DIMX + h * DHEAD) * LKV;
  const bf16_t* vb = kv + (size_t)(b * 2 * DIMX + DIMX + h * DHEAD) * LKV;

  // Q A-fragments, pre-scaled by 1/8
  bf16x8 qf[2];
  {
    const int p = p0 + w * 16 + l15;
#pragma unroll
    for (int c = 0; c < 2; ++c)
#pragma unroll
      for (int i = 0; i < 8; ++i) {
        const int d = c * 32 + g * 8 + i;
        qf[c][i] = (bf16_t)(qb[(size_t)d * HW + p] * 0.125f);
      }
  }

  f32x4 acc[4];
  float m_r[4], l_r[4];
#pragma unroll
  for (int n = 0; n < 4; ++n) { acc[n][0]=0.f; acc[n][1]=0.f; acc[n][2]=0.f; acc[n][3]=0.f; }
#pragma unroll
  for (int r = 0; r < 4; ++r) { m_r[r] = -1e30f; l_r[r] = 0.f; }

  for (int t = 0; t < 13; ++t) {
    const int l0 = t * 64;
    // stage K transposed -> Ks[l][d]; V direct -> Vs[d][l] (pure bf16 moves)
    {
      const int d  = tid >> 2;
      const int lo = (tid & 3) * 16;
#pragma unroll
      for (int jj = 0; jj < 2; ++jj) {
        const int l  = lo + jj * 8;
        const int lg = l0 + l;
        bf16x8 kk, vv;
        if (lg + 8 <= LKV) {           // 784 is 16-aligned: chunks fully in/out
          kk = *(const bf16x8*)(kb + (size_t)d * LKV + lg);
          vv = *(const bf16x8*)(vb + (size_t)d * LKV + lg);
        } else {
#pragma unroll
          for (int k = 0; k < 8; ++k) { kk[k] = (bf16_t)0.f; vv[k] = (bf16_t)0.f; }
        }
#pragma unroll
        for (int k = 0; k < 8; ++k) Ks[l + k][d] = kk[k];
        *(bf16x8*)&Vs[d][l] = vv;
      }
    }
    __syncthreads();

    // QK^T
    f32x4 s[4];
#pragma unroll
    for (int n = 0; n < 4; ++n) {
      f32x4 z; z[0]=0.f; z[1]=0.f; z[2]=0.f; z[3]=0.f;
      const bf16x8 k0 = *(const bf16x8*)&Ks[n * 16 + l15][g * 8];
      const bf16x8 k1 = *(const bf16x8*)&Ks[n * 16 + l15][32 + g * 8];
      z = mfma16(qf[0], k0, z);
      z = mfma16(qf[1], k1, z);
      s[n] = z;
    }
    if (l0 + 64 > LKV) {
#pragma unroll
      for (int n = 0; n < 4; ++n)
        if (l0 + n * 16 + l15 >= LKV) {
#pragma unroll
          for (int r = 0; r < 4; ++r) s[n][r] = -1e30f;
        }
    }

    // online softmax (16-lane row groups)
#pragma unroll
    for (int r = 0; r < 4; ++r) {
      float tm = fmaxf(fmaxf(s[0][r], s[1][r]), fmaxf(s[2][r], s[3][r]));
      tm = fmaxf(tm, __shfl_xor(tm, 1));
      tm = fmaxf(tm, __shfl_xor(tm, 2));
      tm = fmaxf(tm, __shfl_xor(tm, 4));
      tm = fmaxf(tm, __shfl_xor(tm, 8));
      const float mn = fmaxf(m_r[r], tm);
      const float sc = __expf(m_r[r] - mn);
      m_r[r] = mn;
      l_r[r] *= sc;
      float ps = 0.f;
#pragma unroll
      for (int n = 0; n < 4; ++n) {
        const float pv = __expf(s[n][r] - mn);
        s[n][r] = pv;
        ps += pv;
      }
      ps += __shfl_xor(ps, 1);
      ps += __shfl_xor(ps, 2);
      ps += __shfl_xor(ps, 4);
      ps += __shfl_xor(ps, 8);
      l_r[r] += ps;
#pragma unroll
      for (int n = 0; n < 4; ++n) acc[n][r] *= sc;
    }

    // P -> per-wave LDS tile (wave-local)
#pragma unroll
    for (int n = 0; n < 4; ++n)
#pragma unroll
      for (int r = 0; r < 4; ++r)
        Pl[w * 16 + g * 4 + r][n * 16 + l15] = (bf16_t)s[n][r];

    // PV
#pragma unroll
    for (int c2 = 0; c2 < 2; ++c2) {
      const bf16x8 pf = *(const bf16x8*)&Pl[w * 16 + l15][c2 * 32 + g * 8];
#pragma unroll
      for (int n = 0; n < 4; ++n) {
        const bf16x8 vf = *(const bf16x8*)&Vs[n * 16 + l15][c2 * 32 + g * 8];
        acc[n] = mfma16(pf, vf, acc[n]);
      }
    }
    __syncthreads();
  }

  // epilogue: normalize, transpose via LDS, bf16 store
  float inv[4];
#pragma unroll
  for (int r = 0; r < 4; ++r) inv[r] = 1.f / l_r[r];
#pragma unroll
  for (int n = 0; n < 4; ++n)
#pragma unroll
    for (int r = 0; r < 4; ++r)
      Os[n * 16 + l15][w * 16 + g * 4 + r] = acc[n][r] * inv[r];
  __syncthreads();
  {
    const int d  = tid >> 2;
    const int po = (tid & 3) * 16;
    bf16_t* orow = ao + (size_t)(b * DIMX + h * DHEAD + d) * HW + p0 + po;
#pragma unroll
    for (int jj = 0; jj < 2; ++jj) {
      bf16x8 o8;
#pragma unroll
      for (int k = 0; k < 8; ++k) o8[k] = (bf16_t)Os[d][po + jj * 8 + k];
      *(bf16x8*)(orow + jj * 8) = o8;
    }
  }
}

// ---------------------------------------------------------------------------
extern "C" void kernel_launch(void* const* d_in, const int* in_sizes, int n_in,
                              void* d_out, int out_size, void* d_ws, size_t ws_size,
                              hipStream_t stream) {
  const float* x       = (const float*)d_in[0];
  const float* q_w     = (const float*)d_in[1];
  const float* kv_w    = (const float*)d_in[2];
  const float* proj_w  = (const float*)d_in[3];
  const float* proj_b  = (const float*)d_in[4];
  const float* dw_w    = (const float*)d_in[5];
  const float* dw_b    = (const float*)d_in[6];
  const float* bn_w    = (const float*)d_in[7];
  const float* bn_b    = (const float*)d_in[8];
  const float* bn_mean = (const float*)d_in[9];
  const float* bn_var  = (const float*)d_in[10];
  const float* pw_w    = (const float*)d_in[11];
  float* out = (float*)d_out;

  // workspace layout (bytes), total ~83.3 MB
  char* ws = (char*)d_ws;
  float*  qbuf  = (float*)(ws);                       // 38,535,168 B (8,384,3136) f32
  float*  offb  = (float*)(ws + 38535168);            //  9,633,792 B (24,128,784) f32
  float*  gxy   = (float*)(ws + 48168960);            //    150,528 B
  float*  modb  = (float*)(ws + 48319488);            //     75,264 B
  bf16_t* kvb   = (bf16_t*)(ws + 48394752);           //  9,633,792 B (8,768,784) bf16
  bf16_t* xsb   = (bf16_t*)(ws + 58028544);           //  4,816,896 B (24,128,784) bf16
  bf16_t* xbf   = (bf16_t*)(ws + 62845440);           // 19,267,584 B (8,384,3136) bf16
  bf16_t* aob   = xbf;                                // overlay: xbf dead after q-proj
  bf16_t* wbf   = (bf16_t*)(ws + 82113024);           //  1,179,648 B weights bf16
  bf16_t* q_wb  = wbf;                                // 147,456 elems
  bf16_t* kv_wb = wbf + 147456;                       // 294,912 elems
  bf16_t* pj_wb = wbf + 442368;                       // 147,456 elems

  const dim3 blk(256);
  // 0. converts
  cvt_bf16<<<dim3(9408), blk, 0, stream>>>(x, xbf, 2408448);
  cvt_w3<<<dim3(576), blk, 0, stream>>>(q_w, kv_w, proj_w, wbf);
  // 1. q projection (bf16 MFMA, fp32 out for conv path + attn Q)
  gemm_mfma<false, false><<<dim3(49, 6, 8), blk, 0, stream>>>(q_wb, xbf, nullptr, qbuf, 384, 3136, 384);
  // 2. depthwise conv + BN + GELU
  dw_bn_gelu<<<dim3(3072), blk, 0, stream>>>(qbuf, dw_w, dw_b, bn_w, bn_b, bn_mean, bn_var, offb);
  // 3. pointwise -> offsets + (double-sigmoid) modulation -> coords
  om_grid<<<dim3(4, 24), blk, 0, stream>>>(offb, pw_w, gxy, modb);
  // 4. bilinear sample * modulation -> bf16
  sample_mod<<<dim3(3072), blk, 0, stream>>>(x, gxy, modb, xsb);
  // 5. kv projection (bf16 out -> attn staging is pure moves)
  gemm_mfma<false, true><<<dim3(13, 12, 8), blk, 0, stream>>>(kv_wb, xsb, nullptr, kvb, 384, 784, 768);
  // 6. fused attention -> bf16 aob (overlays xbf)
  attn_mfma<<<dim3(49, 6, 8), blk, 0, stream>>>(qbuf, kvb, aob);
  // 7. out projection (+bias) -> d_out fp32 directly
  gemm_mfma<true, false><<<dim3(49, 6, 8), blk, 0, stream>>>(pj_wb, aob, proj_b, out, 384, 3136, 384);
}

// Round 6
// 245.257 us; speedup vs baseline: 4.0947x; 1.1942x over previous
//
#include <hip/hip_runtime.h>
#include <math.h>

#define DIMX 384
#define NHEAD 6
#define DHEAD 64
#define HW 3136   // 56*56
#define LKV 784   // 28*28
#define NGDX 128
#define NGRP 24   // B*3

typedef __bf16 bf16_t;
typedef __bf16 bf16x4 __attribute__((ext_vector_type(4)));
typedef __bf16 bf16x8 __attribute__((ext_vector_type(8)));
typedef float  f32x4  __attribute__((ext_vector_type(4)));

static __device__ __forceinline__ f32x4 mfma16(bf16x8 a, bf16x8 b, f32x4 c) {
  return __builtin_amdgcn_mfma_f32_16x16x32_bf16(a, b, c, 0, 0, 0);
}

// ---------------------------------------------------------------------------
// x (b,c,p) fp32 -> xt (b,p,c) bf16, LDS 64x64 tile transpose
// grid (49, 6, 8), block 256
// ---------------------------------------------------------------------------
__global__ __launch_bounds__(256) void xt_cvt(
    const float* __restrict__ x, bf16_t* __restrict__ xt)
{
  const int p0 = blockIdx.x * 64, c0 = blockIdx.y * 64, b = blockIdx.z;
  __shared__ float T[64][65];
  const int tid = threadIdx.x;
  {
    const int c = tid >> 2, pc = (tid & 3) * 16;
    const float* src = x + ((size_t)b * DIMX + c0 + c) * HW + p0 + pc;
#pragma unroll
    for (int j = 0; j < 4; ++j) {
      const float4 v = *(const float4*)(src + j * 4);
      T[c][pc + j * 4 + 0] = v.x; T[c][pc + j * 4 + 1] = v.y;
      T[c][pc + j * 4 + 2] = v.z; T[c][pc + j * 4 + 3] = v.w;
    }
  }
  __syncthreads();
  {
    const int p = tid >> 2, cc = (tid & 3) * 16;
    bf16_t* dst = xt + ((size_t)b * HW + p0 + p) * DIMX + c0 + cc;
#pragma unroll
    for (int jj = 0; jj < 2; ++jj) {
      bf16x8 o;
#pragma unroll
      for (int k = 0; k < 8; ++k) o[k] = (bf16_t)T[cc + jj * 8 + k][p];
      *(bf16x8*)(dst + jj * 8) = o;
    }
  }
}

// convert the three weight matrices into one bf16 arena
__global__ __launch_bounds__(256) void cvt_w3(
    const float* __restrict__ qw, const float* __restrict__ kvw,
    const float* __restrict__ pw, bf16_t* __restrict__ dst)
{
  const int i = blockIdx.x * 256 + threadIdx.x;
  if (i >= 147456) return;
  const int e = i * 4;
  const float* src;
  int off;
  if (e < 147456)      { src = qw;  off = e; }
  else if (e < 442368) { src = kvw; off = e - 147456; }
  else                 { src = pw;  off = e - 442368; }
  const float4 v = *(const float4*)(src + off);
  bf16x4 o;
  o[0] = (bf16_t)v.x; o[1] = (bf16_t)v.y; o[2] = (bf16_t)v.z; o[3] = (bf16_t)v.w;
  *(bf16x4*)(dst + e) = o;
}

// ---------------------------------------------------------------------------
// bf16 MFMA GEMM: out[b,o,p] = sum_c W[o,c]*in[b,c,p] (+bias)
// BTRANS: in is (b,p,c) -> vector B staging. KSPLIT: o<384 -> K transposed
// [b,h,l,d]; o>=384 -> V [b,c,l].
// ---------------------------------------------------------------------------
template<bool BIAS, bool OBF16, bool BTRANS, bool KSPLIT>
__global__ __launch_bounds__(256) void gemm_mfma(
    const bf16_t* __restrict__ W, const bf16_t* __restrict__ in,
    const float* __restrict__ bias, void* __restrict__ out0,
    void* __restrict__ out1, int C, int P, int O)
{
  const int b  = blockIdx.z;
  const int o0 = blockIdx.y * 64;
  const int p0 = blockIdx.x * 64;
  __shared__ __align__(16) bf16_t As[64][72];   // [o][c]
  __shared__ __align__(16) bf16_t Bs[64][72];   // [p][c]
  const int tid = threadIdx.x;
  const int w = tid >> 6, lane = tid & 63, l15 = lane & 15, g = lane >> 4;

  f32x4 acc[4];
#pragma unroll
  for (int n = 0; n < 4; ++n) { acc[n][0]=0.f; acc[n][1]=0.f; acc[n][2]=0.f; acc[n][3]=0.f; }

  for (int c0 = 0; c0 < C; c0 += 64) {
    {
      const int o = tid >> 2, cc = (tid & 3) * 16;
      const bf16_t* src = W + (size_t)(o0 + o) * C + c0 + cc;
      *(bf16x8*)&As[o][cc]     = *(const bf16x8*)src;
      *(bf16x8*)&As[o][cc + 8] = *(const bf16x8*)(src + 8);
    }
    if (BTRANS) {
      // in (b,p,c): vector rows
      const int pp = tid >> 2, cc = (tid & 3) * 16;
      const bf16_t* src = in + ((size_t)b * P + p0 + pp) * C + c0 + cc;
      *(bf16x8*)&Bs[pp][cc]     = *(const bf16x8*)src;
      *(bf16x8*)&Bs[pp][cc + 8] = *(const bf16x8*)(src + 8);
    } else {
      // in (b,c,p): transpose scatter
      const int c = tid >> 2, pp = (tid & 3) * 16;
      const bf16_t* src = in + ((size_t)b * C + c0 + c) * P + p0 + pp;
#pragma unroll
      for (int jj = 0; jj < 2; ++jj) {
        bf16x8 v;
        if (p0 + pp + jj * 8 + 8 <= P) v = *(const bf16x8*)(src + jj * 8);
        else {
#pragma unroll
          for (int k = 0; k < 8; ++k) v[k] = (bf16_t)0.f;
        }
#pragma unroll
        for (int k = 0; k < 8; ++k) Bs[pp + jj * 8 + k][c] = v[k];
      }
    }
    __syncthreads();
#pragma unroll
    for (int ks = 0; ks < 2; ++ks) {
      const bf16x8 af = *(const bf16x8*)&As[w * 16 + l15][ks * 32 + g * 8];
#pragma unroll
      for (int n = 0; n < 4; ++n) {
        const bf16x8 bfr = *(const bf16x8*)&Bs[n * 16 + l15][ks * 32 + g * 8];
        acc[n] = mfma16(af, bfr, acc[n]);
      }
    }
    __syncthreads();
  }

  if (KSPLIT) {
    if (blockIdx.y < 6) {
      // K half: kt[b][h][l][d], d = w*16+g*4+r (contiguous in r)
      const int h = blockIdx.y;
      bf16_t* kt = (bf16_t*)out0;
#pragma unroll
      for (int n = 0; n < 4; ++n) {
        const int l = p0 + n * 16 + l15;
        if (l < P) {
          bf16x4 kq;
#pragma unroll
          for (int r = 0; r < 4; ++r) kq[r] = (bf16_t)acc[n][r];
          *(bf16x4*)&kt[(((size_t)b * NHEAD + h) * LKV + l) * DHEAD + w * 16 + g * 4] = kq;
        }
      }
    } else {
      // V half: vt[b][c][l], c = o0-384 + w*16+g*4+r
      bf16_t* vt = (bf16_t*)out1;
#pragma unroll
      for (int n = 0; n < 4; ++n) {
        const int p = p0 + n * 16 + l15;
        if (p < P) {
#pragma unroll
          for (int r = 0; r < 4; ++r) {
            const int c = o0 - DIMX + w * 16 + g * 4 + r;
            vt[((size_t)b * DIMX + c) * LKV + p] = (bf16_t)acc[n][r];
          }
        }
      }
    }
    return;
  }

  float badd[4];
#pragma unroll
  for (int r = 0; r < 4; ++r) badd[r] = BIAS ? bias[o0 + w * 16 + g * 4 + r] : 0.f;
#pragma unroll
  for (int n = 0; n < 4; ++n) {
    const int p = p0 + n * 16 + l15;
    if (p < P) {
#pragma unroll
      for (int r = 0; r < 4; ++r) {
        const int o = o0 + w * 16 + g * 4 + r;
        const float v = acc[n][r] + badd[r];
        if (OBF16) ((bf16_t*)out0)[((size_t)b * O + o) * P + p] = (bf16_t)v;
        else       ((float*)out0)[((size_t)b * O + o) * P + p] = v;
      }
    }
  }
}

// ---------------------------------------------------------------------------
// Depthwise 5x5 stride-2 conv + bias + BN + exact GELU (fp32)
// ---------------------------------------------------------------------------
__global__ __launch_bounds__(256) void dw_bn_gelu(
    const float* __restrict__ q, const float* __restrict__ dw_w,
    const float* __restrict__ dw_b, const float* __restrict__ bn_w,
    const float* __restrict__ bn_b, const float* __restrict__ bn_mean,
    const float* __restrict__ bn_var, float* __restrict__ off)
{
  const int nc = blockIdx.x;
  const int c  = nc & 127;
  const float* plane = q + (size_t)nc * HW;
  float w[25];
#pragma unroll
  for (int k = 0; k < 25; ++k) w[k] = dw_w[c * 25 + k];
  const float beta  = dw_b[c];
  const float scale = bn_w[c] * rsqrtf(bn_var[c] + 1e-6f);
  const float shift = bn_b[c] - bn_mean[c] * scale;

  for (int p = threadIdx.x; p < LKV; p += 256) {
    const int oy = p / 28, ox = p % 28;
    const int iy0 = oy * 2 - 2, ix0 = ox * 2 - 2;
    float s = 0.f;
#pragma unroll
    for (int ky = 0; ky < 5; ++ky) {
      const int y = iy0 + ky;
      if ((unsigned)y >= 56u) continue;
#pragma unroll
      for (int kx = 0; kx < 5; ++kx) {
        const int x = ix0 + kx;
        if ((unsigned)x >= 56u) continue;
        s += plane[y * 56 + x] * w[ky * 5 + kx];
      }
    }
    s = (s + beta) * scale + shift;
    const float g = 0.5f * s * (1.f + erff(s * 0.70710678118654752f));
    off[(size_t)nc * LKV + p] = g;
  }
}

// ---------------------------------------------------------------------------
// Pointwise (3,128) -> offsets / double-sigmoid modulation -> sample coords
// ---------------------------------------------------------------------------
__global__ __launch_bounds__(256) void om_grid(
    const float* __restrict__ off, const float* __restrict__ pw_w,
    float* __restrict__ gxy, float* __restrict__ modb)
{
  const int n = blockIdx.y;
  const int p = blockIdx.x * 256 + threadIdx.x;
  if (p >= LKV) return;
  const float* base = off + (size_t)n * NGDX * LKV + p;
  float s0 = 0.f, s1 = 0.f, s2 = 0.f;
  for (int c = 0; c < NGDX; ++c) {
    const float v = base[(size_t)c * LKV];
    s0 += v * pw_w[c];
    s1 += v * pw_w[128 + c];
    s2 += v * pw_w[256 + c];
  }
  const float sig1 = 1.f / (1.f + expf(-s2));
  const float mod  = 1.f / (1.f + expf(-sig1));   // double sigmoid (per reference)
  const float offy = tanhf(s0) * (2.f / 28.f);
  const float offx = tanhf(s1) * (2.f / 28.f);
  const int i = p / 28, j = p % 28;
  const float refy = ((i + 0.5f) / 28.f) * 2.f - 1.f;
  const float refx = ((j + 0.5f) / 28.f) * 2.f - 1.f;
  const float gy = (offy + refy + 1.f) * 0.5f * 55.f;
  const float gx = (offx + refx + 1.f) * 0.5f * 55.f;
  gxy[((size_t)n * LKV + p) * 2 + 0] = gx;
  gxy[((size_t)n * LKV + p) * 2 + 1] = gy;
  modb[(size_t)n * LKV + p] = mod;
}

// ---------------------------------------------------------------------------
// Bilinear sample * modulation -> bf16 (c-major, feeds kv GEMM scatter path)
// ---------------------------------------------------------------------------
__global__ __launch_bounds__(256) void sample_mod(
    const float* __restrict__ x, const float* __restrict__ gxy,
    const float* __restrict__ modb, bf16_t* __restrict__ xs)
{
  const int nc = blockIdx.x;
  const int n  = nc >> 7;
  const float* img = x + (size_t)nc * HW;
  for (int p = threadIdx.x; p < LKV; p += 256) {
    const float gx = gxy[((size_t)n * LKV + p) * 2 + 0];
    const float gy = gxy[((size_t)n * LKV + p) * 2 + 1];
    const float x0f = floorf(gx), y0f = floorf(gy);
    const float wx1 = gx - x0f, wy1 = gy - y0f;
    const float wx0 = (x0f + 1.f) - gx, wy0 = (y0f + 1.f) - gy;
    const int ix0 = (int)x0f, iy0 = (int)y0f;
    const int ix1 = ix0 + 1,  iy1 = iy0 + 1;
    const bool vx0 = (ix0 >= 0) && (ix0 < 56), vx1 = (ix1 >= 0) && (ix1 < 56);
    const bool vy0 = (iy0 >= 0) && (iy0 < 56), vy1 = (iy1 >= 0) && (iy1 < 56);
    const int cx0 = min(max(ix0, 0), 55), cx1 = min(max(ix1, 0), 55);
    const int cy0 = min(max(iy0, 0), 55), cy1 = min(max(iy1, 0), 55);
    const float f00 = (vy0 && vx0) ? img[cy0 * 56 + cx0] : 0.f;
    const float f10 = (vy1 && vx0) ? img[cy1 * 56 + cx0] : 0.f;
    const float f01 = (vy0 && vx1) ? img[cy0 * 56 + cx1] : 0.f;
    const float f11 = (vy1 && vx1) ? img[cy1 * 56 + cx1] : 0.f;
    const float v = f00 * (wx0 * wy0) + f10 * (wx0 * wy1)
                  + f01 * (wx1 * wy0) + f11 * (wx1 * wy1);
    xs[(size_t)nc * LKV + p] = (bf16_t)(v * modb[(size_t)n * LKV + p]);
  }
}

// ---------------------------------------------------------------------------
// bf16 MFMA attention, no-max softmax (scores are tiny: exp2 with prefolded
// 0.125*log2e scale; P=exp2(s); l = per-lane partials reduced once at end).
// Q tile 128 (32 rows/wave), K pre-transposed [b,h,l,d], V [b,c,l].
// grid (25, 6, 8), block 256. Output aot (b,p,c) bf16.
// ---------------------------------------------------------------------------
__global__ __launch_bounds__(256) void attn_mfma(
    const float* __restrict__ q, const bf16_t* __restrict__ kt,
    const bf16_t* __restrict__ vt, bf16_t* __restrict__ aot)
{
  const int p0 = blockIdx.x * 128;
  const int h  = blockIdx.y;
  const int b  = blockIdx.z;

  __shared__ __align__(16) char smem[36864];
  bf16_t (*Ks)[72] = (bf16_t(*)[72])(smem);          // [l][d]
  bf16_t (*Vs)[72] = (bf16_t(*)[72])(smem + 9216);   // [d][l]
  bf16_t (*Pl)[72] = (bf16_t(*)[72])(smem + 18432);  // [128 rows][l]
  float  (*Os)[68] = (float (*)[68])(smem);          // epilogue [128 p][d]

  const int tid  = threadIdx.x;
  const int w    = tid >> 6;
  const int lane = tid & 63;
  const int l15  = lane & 15;
  const int g    = lane >> 4;

  const float*  qb = q  + (size_t)(b * DIMX + h * DHEAD) * HW;
  const bf16_t* kb = kt + ((size_t)(b * NHEAD + h) * LKV) * DHEAD;
  const bf16_t* vb = vt + (size_t)(b * DIMX + h * DHEAD) * LKV;

  // Q A-frags, scale = 0.125 * log2(e)
  const float QSCL = 0.18033688011112042f;
  bf16x8 qf[2][2];
#pragma unroll
  for (int rs = 0; rs < 2; ++rs) {
    const int p = p0 + w * 32 + rs * 16 + l15;
    const bool valid = p < HW;
#pragma unroll
    for (int c2 = 0; c2 < 2; ++c2)
#pragma unroll
      for (int i = 0; i < 8; ++i) {
        const int d = c2 * 32 + g * 8 + i;
        qf[rs][c2][i] = valid ? (bf16_t)(qb[(size_t)d * HW + p] * QSCL) : (bf16_t)0.f;
      }
  }

  f32x4 acc[2][4];
  float lsum[2][4];
#pragma unroll
  for (int rs = 0; rs < 2; ++rs)
#pragma unroll
    for (int n = 0; n < 4; ++n) {
      acc[rs][n][0]=0.f; acc[rs][n][1]=0.f; acc[rs][n][2]=0.f; acc[rs][n][3]=0.f;
      lsum[rs][n] = 0.f;
    }

  for (int t = 0; t < 13; ++t) {
    const int l0 = t * 64;
    // stage K rows (vector copy, [l][d])
    {
      const int l = tid >> 2, d0 = (tid & 3) * 16;
      const int lg = l0 + l;
      if (lg < LKV) {
        const bf16_t* src = kb + (size_t)lg * DHEAD + d0;
        *(bf16x8*)&Ks[l][d0]     = *(const bf16x8*)src;
        *(bf16x8*)&Ks[l][d0 + 8] = *(const bf16x8*)(src + 8);
      } else {
        bf16x8 z;
#pragma unroll
        for (int k = 0; k < 8; ++k) z[k] = (bf16_t)0.f;
        *(bf16x8*)&Ks[l][d0] = z;
        *(bf16x8*)&Ks[l][d0 + 8] = z;
      }
    }
    // stage V rows ([d][l])
    {
      const int d = tid >> 2, lc = (tid & 3) * 16;
#pragma unroll
      for (int jj = 0; jj < 2; ++jj) {
        const int lg = l0 + lc + jj * 8;
        bf16x8 v;
        if (lg + 8 <= LKV) v = *(const bf16x8*)(vb + (size_t)d * LKV + lg);
        else {
#pragma unroll
          for (int k = 0; k < 8; ++k) v[k] = (bf16_t)0.f;
        }
        *(bf16x8*)&Vs[d][lc + jj * 8] = v;
      }
    }
    __syncthreads();

    // QK^T
    f32x4 s[2][4];
#pragma unroll
    for (int rs = 0; rs < 2; ++rs)
#pragma unroll
      for (int n = 0; n < 4; ++n) {
        f32x4 z; z[0]=0.f; z[1]=0.f; z[2]=0.f; z[3]=0.f;
        z = mfma16(qf[rs][0], *(const bf16x8*)&Ks[n * 16 + l15][g * 8], z);
        z = mfma16(qf[rs][1], *(const bf16x8*)&Ks[n * 16 + l15][32 + g * 8], z);
        s[rs][n] = z;
      }
    if (l0 + 64 > LKV) {
#pragma unroll
      for (int n = 0; n < 4; ++n)
        if (l0 + n * 16 + l15 >= LKV) {
#pragma unroll
          for (int rs = 0; rs < 2; ++rs)
#pragma unroll
            for (int r = 0; r < 4; ++r) s[rs][n][r] = -1e30f;
        }
    }

    // P = exp2(s); accumulate per-lane l partials; scatter P to wave-local LDS
#pragma unroll
    for (int rs = 0; rs < 2; ++rs)
#pragma unroll
      for (int n = 0; n < 4; ++n)
#pragma unroll
        for (int r = 0; r < 4; ++r) {
          const float pv = exp2f(s[rs][n][r]);
          lsum[rs][r] += pv;
          Pl[w * 32 + rs * 16 + g * 4 + r][n * 16 + l15] = (bf16_t)pv;
        }

    // PV
#pragma unroll
    for (int rs = 0; rs < 2; ++rs)
#pragma unroll
      for (int c2 = 0; c2 < 2; ++c2) {
        const bf16x8 pf = *(const bf16x8*)&Pl[w * 32 + rs * 16 + l15][c2 * 32 + g * 8];
#pragma unroll
        for (int n = 0; n < 4; ++n)
          acc[rs][n] = mfma16(pf, *(const bf16x8*)&Vs[n * 16 + l15][c2 * 32 + g * 8], acc[rs][n]);
      }
    __syncthreads();
  }

  // epilogue: reduce l across 16 lanes (once), normalize, transpose, store
#pragma unroll
  for (int rs = 0; rs < 2; ++rs)
#pragma unroll
    for (int r = 0; r < 4; ++r) {
      float red = lsum[rs][r];
      red += __shfl_xor(red, 1);
      red += __shfl_xor(red, 2);
      red += __shfl_xor(red, 4);
      red += __shfl_xor(red, 8);
      const float inv = 1.f / red;
#pragma unroll
      for (int n = 0; n < 4; ++n)
        Os[w * 32 + rs * 16 + g * 4 + r][n * 16 + l15] = acc[rs][n][r] * inv;
    }
  __syncthreads();
  {
    const int pr = tid >> 1, c0 = (tid & 1) * 32;
    const int p = p0 + pr;
    if (p < HW) {
      bf16_t* dst = aot + ((size_t)b * HW + p) * DIMX + h * DHEAD + c0;
#pragma unroll
      for (int jj = 0; jj < 4; ++jj) {
        bf16x8 o8;
#pragma unroll
        for (int k = 0; k < 8; ++k) o8[k] = (bf16_t)Os[pr][c0 + jj * 8 + k];
        *(bf16x8*)(dst + jj * 8) = o8;
      }
    }
  }
}

// ---------------------------------------------------------------------------
extern "C" void kernel_launch(void* const* d_in, const int* in_sizes, int n_in,
                              void* d_out, int out_size, void* d_ws, size_t ws_size,
                              hipStream_t stream) {
  const float* x       = (const float*)d_in[0];
  const float* q_w     = (const float*)d_in[1];
  const float* kv_w    = (const float*)d_in[2];
  const float* proj_w  = (const float*)d_in[3];
  const float* proj_b  = (const float*)d_in[4];
  const float* dw_w    = (const float*)d_in[5];
  const float* dw_b    = (const float*)d_in[6];
  const float* bn_w    = (const float*)d_in[7];
  const float* bn_b    = (const float*)d_in[8];
  const float* bn_mean = (const float*)d_in[9];
  const float* bn_var  = (const float*)d_in[10];
  const float* pw_w    = (const float*)d_in[11];
  float* out = (float*)d_out;

  // workspace (bytes), total ~83.3 MB
  char* ws = (char*)d_ws;
  float*  qbuf  = (float*)(ws);                       // 38,535,168 (8,384,3136) f32
  float*  offb  = (float*)(ws + 38535168);            //  9,633,792 (24,128,784) f32
  float*  gxy   = (float*)(ws + 48168960);            //    150,528
  float*  modb  = (float*)(ws + 48319488);            //     75,264
  bf16_t* ktb   = (bf16_t*)(ws + 48394752);           //  4,816,896 (8,6,784,64) bf16
  bf16_t* vtb   = (bf16_t*)(ws + 53211648);           //  4,816,896 (8,384,784) bf16
  bf16_t* xsb   = (bf16_t*)(ws + 58028544);           //  4,816,896 (24,128,784) bf16
  bf16_t* xt    = (bf16_t*)(ws + 62845440);           // 19,267,584 (8,3136,384) bf16
  bf16_t* aot   = xt;                                 // overlay: xt dead after q-proj
  bf16_t* wbf   = (bf16_t*)(ws + 82113024);           //  1,179,648 weights bf16
  bf16_t* q_wb  = wbf;
  bf16_t* kv_wb = wbf + 147456;
  bf16_t* pj_wb = wbf + 442368;

  const dim3 blk(256);
  // 0. converts
  xt_cvt<<<dim3(49, 6, 8), blk, 0, stream>>>(x, xt);
  cvt_w3<<<dim3(576), blk, 0, stream>>>(q_w, kv_w, proj_w, wbf);
  // 1. q projection (BTRANS in, fp32 out)
  gemm_mfma<false, false, true, false><<<dim3(49, 6, 8), blk, 0, stream>>>(
      q_wb, xt, nullptr, qbuf, nullptr, 384, 3136, 384);
  // 2. depthwise conv + BN + GELU
  dw_bn_gelu<<<dim3(3072), blk, 0, stream>>>(qbuf, dw_w, dw_b, bn_w, bn_b, bn_mean, bn_var, offb);
  // 3. pointwise -> offsets + (double-sigmoid) modulation -> coords
  om_grid<<<dim3(4, 24), blk, 0, stream>>>(offb, pw_w, gxy, modb);
  // 4. bilinear sample * modulation -> bf16 (c-major)
  sample_mod<<<dim3(3072), blk, 0, stream>>>(x, gxy, modb, xsb);
  // 5. kv projection -> K transposed [b,h,l,d] + V [b,c,l]
  gemm_mfma<false, false, false, true><<<dim3(13, 12, 8), blk, 0, stream>>>(
      kv_wb, xsb, nullptr, ktb, vtb, 384, 784, 768);
  // 6. attention (no-max softmax) -> aot (b,p,c) bf16
  attn_mfma<<<dim3(25, 6, 8), blk, 0, stream>>>(qbuf, ktb, vtb, aot);
  // 7. out projection (+bias, BTRANS in) -> d_out fp32
  gemm_mfma<true, false, true, false><<<dim3(49, 6, 8), blk, 0, stream>>>(
      pj_wb, aot, proj_b, out, nullptr, 384, 3136, 384);
}

// Round 7
// 234.760 us; speedup vs baseline: 4.2778x; 1.0447x over previous
//
#include <hip/hip_runtime.h>
#include <math.h>

#define DIMX 384
#define NHEAD 6
#define DHEAD 64
#define HW 3136   // 56*56
#define LKV 784   // 28*28
#define NGDX 128
#define NGRP 24   // B*3

typedef __bf16 bf16_t;
typedef __bf16 bf16x4 __attribute__((ext_vector_type(4)));
typedef __bf16 bf16x8 __attribute__((ext_vector_type(8)));
typedef float  f32x4  __attribute__((ext_vector_type(4)));

static __device__ __forceinline__ f32x4 mfma16(bf16x8 a, bf16x8 b, f32x4 c) {
  return __builtin_amdgcn_mfma_f32_16x16x32_bf16(a, b, c, 0, 0, 0);
}

// ---------------------------------------------------------------------------
// x (b,c,p) fp32 -> xt (b,p,c) bf16, LDS 64x64 tile transpose
// ---------------------------------------------------------------------------
__global__ __launch_bounds__(256) void xt_cvt(
    const float* __restrict__ x, bf16_t* __restrict__ xt)
{
  const int p0 = blockIdx.x * 64, c0 = blockIdx.y * 64, b = blockIdx.z;
  __shared__ float T[64][65];
  const int tid = threadIdx.x;
  {
    const int c = tid >> 2, pc = (tid & 3) * 16;
    const float* src = x + ((size_t)b * DIMX + c0 + c) * HW + p0 + pc;
#pragma unroll
    for (int j = 0; j < 4; ++j) {
      const float4 v = *(const float4*)(src + j * 4);
      T[c][pc + j * 4 + 0] = v.x; T[c][pc + j * 4 + 1] = v.y;
      T[c][pc + j * 4 + 2] = v.z; T[c][pc + j * 4 + 3] = v.w;
    }
  }
  __syncthreads();
  {
    const int p = tid >> 2, cc = (tid & 3) * 16;
    bf16_t* dst = xt + ((size_t)b * HW + p0 + p) * DIMX + c0 + cc;
#pragma unroll
    for (int jj = 0; jj < 2; ++jj) {
      bf16x8 o;
#pragma unroll
      for (int k = 0; k < 8; ++k) o[k] = (bf16_t)T[cc + jj * 8 + k][p];
      *(bf16x8*)(dst + jj * 8) = o;
    }
  }
}

// convert the three weight matrices into one bf16 arena
__global__ __launch_bounds__(256) void cvt_w3(
    const float* __restrict__ qw, const float* __restrict__ kvw,
    const float* __restrict__ pw, bf16_t* __restrict__ dst)
{
  const int i = blockIdx.x * 256 + threadIdx.x;
  if (i >= 147456) return;
  const int e = i * 4;
  const float* src;
  int off;
  if (e < 147456)      { src = qw;  off = e; }
  else if (e < 442368) { src = kvw; off = e - 147456; }
  else                 { src = pw;  off = e - 442368; }
  const float4 v = *(const float4*)(src + off);
  bf16x4 o;
  o[0] = (bf16_t)v.x; o[1] = (bf16_t)v.y; o[2] = (bf16_t)v.z; o[3] = (bf16_t)v.w;
  *(bf16x4*)(dst + e) = o;
}

// ---------------------------------------------------------------------------
// bf16 MFMA GEMM: out[b,o,p] = sum_c W[o,c]*in[b,c,p] (+bias)
// BTRANS: in is (b,p,c) -> vector B staging. KSPLIT: o<384 -> K transposed
// [b,h,l,d]; o>=384 -> V [b,c,l].
// ---------------------------------------------------------------------------
template<bool BIAS, bool OBF16, bool BTRANS, bool KSPLIT>
__global__ __launch_bounds__(256) void gemm_mfma(
    const bf16_t* __restrict__ W, const bf16_t* __restrict__ in,
    const float* __restrict__ bias, void* __restrict__ out0,
    void* __restrict__ out1, int C, int P, int O)
{
  const int b  = blockIdx.z;
  const int o0 = blockIdx.y * 64;
  const int p0 = blockIdx.x * 64;
  __shared__ __align__(16) bf16_t As[64][72];   // [o][c]
  __shared__ __align__(16) bf16_t Bs[64][72];   // [p][c]
  const int tid = threadIdx.x;
  const int w = tid >> 6, lane = tid & 63, l15 = lane & 15, g = lane >> 4;

  f32x4 acc[4];
#pragma unroll
  for (int n = 0; n < 4; ++n) { acc[n][0]=0.f; acc[n][1]=0.f; acc[n][2]=0.f; acc[n][3]=0.f; }

  for (int c0 = 0; c0 < C; c0 += 64) {
    {
      const int o = tid >> 2, cc = (tid & 3) * 16;
      const bf16_t* src = W + (size_t)(o0 + o) * C + c0 + cc;
      *(bf16x8*)&As[o][cc]     = *(const bf16x8*)src;
      *(bf16x8*)&As[o][cc + 8] = *(const bf16x8*)(src + 8);
    }
    if (BTRANS) {
      const int pp = tid >> 2, cc = (tid & 3) * 16;
      const bf16_t* src = in + ((size_t)b * P + p0 + pp) * C + c0 + cc;
      *(bf16x8*)&Bs[pp][cc]     = *(const bf16x8*)src;
      *(bf16x8*)&Bs[pp][cc + 8] = *(const bf16x8*)(src + 8);
    } else {
      const int c = tid >> 2, pp = (tid & 3) * 16;
      const bf16_t* src = in + ((size_t)b * C + c0 + c) * P + p0 + pp;
#pragma unroll
      for (int jj = 0; jj < 2; ++jj) {
        bf16x8 v;
        if (p0 + pp + jj * 8 + 8 <= P) v = *(const bf16x8*)(src + jj * 8);
        else {
#pragma unroll
          for (int k = 0; k < 8; ++k) v[k] = (bf16_t)0.f;
        }
#pragma unroll
        for (int k = 0; k < 8; ++k) Bs[pp + jj * 8 + k][c] = v[k];
      }
    }
    __syncthreads();
#pragma unroll
    for (int ks = 0; ks < 2; ++ks) {
      const bf16x8 af = *(const bf16x8*)&As[w * 16 + l15][ks * 32 + g * 8];
#pragma unroll
      for (int n = 0; n < 4; ++n) {
        const bf16x8 bfr = *(const bf16x8*)&Bs[n * 16 + l15][ks * 32 + g * 8];
        acc[n] = mfma16(af, bfr, acc[n]);
      }
    }
    __syncthreads();
  }

  if (KSPLIT) {
    if (blockIdx.y < 6) {
      const int h = blockIdx.y;
      bf16_t* kt = (bf16_t*)out0;
#pragma unroll
      for (int n = 0; n < 4; ++n) {
        const int l = p0 + n * 16 + l15;
        if (l < P) {
          bf16x4 kq;
#pragma unroll
          for (int r = 0; r < 4; ++r) kq[r] = (bf16_t)acc[n][r];
          *(bf16x4*)&kt[(((size_t)b * NHEAD + h) * LKV + l) * DHEAD + w * 16 + g * 4] = kq;
        }
      }
    } else {
      bf16_t* vt = (bf16_t*)out1;
#pragma unroll
      for (int n = 0; n < 4; ++n) {
        const int p = p0 + n * 16 + l15;
        if (p < P) {
#pragma unroll
          for (int r = 0; r < 4; ++r) {
            const int c = o0 - DIMX + w * 16 + g * 4 + r;
            vt[((size_t)b * DIMX + c) * LKV + p] = (bf16_t)acc[n][r];
          }
        }
      }
    }
    return;
  }

  float badd[4];
#pragma unroll
  for (int r = 0; r < 4; ++r) badd[r] = BIAS ? bias[o0 + w * 16 + g * 4 + r] : 0.f;
#pragma unroll
  for (int n = 0; n < 4; ++n) {
    const int p = p0 + n * 16 + l15;
    if (p < P) {
#pragma unroll
      for (int r = 0; r < 4; ++r) {
        const int o = o0 + w * 16 + g * 4 + r;
        const float v = acc[n][r] + badd[r];
        if (OBF16) ((bf16_t*)out0)[((size_t)b * O + o) * P + p] = (bf16_t)v;
        else       ((float*)out0)[((size_t)b * O + o) * P + p] = v;
      }
    }
  }
}

// ---------------------------------------------------------------------------
// Depthwise 5x5 stride-2 conv + bias + BN + exact GELU (fp32)
// ---------------------------------------------------------------------------
__global__ __launch_bounds__(256) void dw_bn_gelu(
    const float* __restrict__ q, const float* __restrict__ dw_w,
    const float* __restrict__ dw_b, const float* __restrict__ bn_w,
    const float* __restrict__ bn_b, const float* __restrict__ bn_mean,
    const float* __restrict__ bn_var, float* __restrict__ off)
{
  const int nc = blockIdx.x;
  const int c  = nc & 127;
  const float* plane = q + (size_t)nc * HW;
  float w[25];
#pragma unroll
  for (int k = 0; k < 25; ++k) w[k] = dw_w[c * 25 + k];
  const float beta  = dw_b[c];
  const float scale = bn_w[c] * rsqrtf(bn_var[c] + 1e-6f);
  const float shift = bn_b[c] - bn_mean[c] * scale;

  for (int p = threadIdx.x; p < LKV; p += 256) {
    const int oy = p / 28, ox = p % 28;
    const int iy0 = oy * 2 - 2, ix0 = ox * 2 - 2;
    float s = 0.f;
#pragma unroll
    for (int ky = 0; ky < 5; ++ky) {
      const int y = iy0 + ky;
      if ((unsigned)y >= 56u) continue;
#pragma unroll
      for (int kx = 0; kx < 5; ++kx) {
        const int x = ix0 + kx;
        if ((unsigned)x >= 56u) continue;
        s += plane[y * 56 + x] * w[ky * 5 + kx];
      }
    }
    s = (s + beta) * scale + shift;
    const float g = 0.5f * s * (1.f + erff(s * 0.70710678118654752f));
    off[(size_t)nc * LKV + p] = g;
  }
}

// ---------------------------------------------------------------------------
// Pointwise (3,128) -> offsets / double-sigmoid modulation -> sample coords
// ---------------------------------------------------------------------------
__global__ __launch_bounds__(256) void om_grid(
    const float* __restrict__ off, const float* __restrict__ pw_w,
    float* __restrict__ gxy, float* __restrict__ modb)
{
  const int n = blockIdx.y;
  const int p = blockIdx.x * 256 + threadIdx.x;
  if (p >= LKV) return;
  const float* base = off + (size_t)n * NGDX * LKV + p;
  float s0 = 0.f, s1 = 0.f, s2 = 0.f;
  for (int c = 0; c < NGDX; ++c) {
    const float v = base[(size_t)c * LKV];
    s0 += v * pw_w[c];
    s1 += v * pw_w[128 + c];
    s2 += v * pw_w[256 + c];
  }
  const float sig1 = 1.f / (1.f + expf(-s2));
  const float mod  = 1.f / (1.f + expf(-sig1));   // double sigmoid (per reference)
  const float offy = tanhf(s0) * (2.f / 28.f);
  const float offx = tanhf(s1) * (2.f / 28.f);
  const int i = p / 28, j = p % 28;
  const float refy = ((i + 0.5f) / 28.f) * 2.f - 1.f;
  const float refx = ((j + 0.5f) / 28.f) * 2.f - 1.f;
  const float gy = (offy + refy + 1.f) * 0.5f * 55.f;
  const float gx = (offx + refx + 1.f) * 0.5f * 55.f;
  gxy[((size_t)n * LKV + p) * 2 + 0] = gx;
  gxy[((size_t)n * LKV + p) * 2 + 1] = gy;
  modb[(size_t)n * LKV + p] = mod;
}

// ---------------------------------------------------------------------------
// Bilinear sample * modulation -> bf16 (c-major, feeds kv GEMM scatter path)
// ---------------------------------------------------------------------------
__global__ __launch_bounds__(256) void sample_mod(
    const float* __restrict__ x, const float* __restrict__ gxy,
    const float* __restrict__ modb, bf16_t* __restrict__ xs)
{
  const int nc = blockIdx.x;
  const int n  = nc >> 7;
  const float* img = x + (size_t)nc * HW;
  for (int p = threadIdx.x; p < LKV; p += 256) {
    const float gx = gxy[((size_t)n * LKV + p) * 2 + 0];
    const float gy = gxy[((size_t)n * LKV + p) * 2 + 1];
    const float x0f = floorf(gx), y0f = floorf(gy);
    const float wx1 = gx - x0f, wy1 = gy - y0f;
    const float wx0 = (x0f + 1.f) - gx, wy0 = (y0f + 1.f) - gy;
    const int ix0 = (int)x0f, iy0 = (int)y0f;
    const int ix1 = ix0 + 1,  iy1 = iy0 + 1;
    const bool vx0 = (ix0 >= 0) && (ix0 < 56), vx1 = (ix1 >= 0) && (ix1 < 56);
    const bool vy0 = (iy0 >= 0) && (iy0 < 56), vy1 = (iy1 >= 0) && (iy1 < 56);
    const int cx0 = min(max(ix0, 0), 55), cx1 = min(max(ix1, 0), 55);
    const int cy0 = min(max(iy0, 0), 55), cy1 = min(max(iy1, 0), 55);
    const float f00 = (vy0 && vx0) ? img[cy0 * 56 + cx0] : 0.f;
    const float f10 = (vy1 && vx0) ? img[cy1 * 56 + cx0] : 0.f;
    const float f01 = (vy0 && vx1) ? img[cy0 * 56 + cx1] : 0.f;
    const float f11 = (vy1 && vx1) ? img[cy1 * 56 + cx1] : 0.f;
    const float v = f00 * (wx0 * wy0) + f10 * (wx0 * wy1)
                  + f01 * (wx1 * wy0) + f11 * (wx1 * wy1);
    xs[(size_t)nc * LKV + p] = (bf16_t)(v * modb[(size_t)n * LKV + p]);
  }
}

// ---------------------------------------------------------------------------
// bf16 MFMA attention, swapped-operand QK^T + no-max softmax.
// S^T = mfma(K, Q): row=l, col=q -> per-lane P values contiguous in l ->
// packed b64 P writes into per-wave LDS tile Pt[q][l]; PV = mfma(V^T, P^T)
// gives O^T (row=d, col=q) -> packed f32x4 epilogue.
// grid (25, 6, 8), block 256 (4 waves x 32 q-rows). Output aot (b,p,c) bf16.
// ---------------------------------------------------------------------------
__global__ __launch_bounds__(256) void attn_mfma(
    const float* __restrict__ q, const bf16_t* __restrict__ kt,
    const bf16_t* __restrict__ vt, bf16_t* __restrict__ aot)
{
  const int p0 = blockIdx.x * 128;
  const int h  = blockIdx.y;
  const int b  = blockIdx.z;

  __shared__ __align__(16) char smem[36864];
  bf16_t (*Ks)[72] = (bf16_t(*)[72])(smem);          // [l 64][d]
  bf16_t (*Vs)[72] = (bf16_t(*)[72])(smem + 9216);   // [d 64][l]
  bf16_t (*Pt)[72] = (bf16_t(*)[72])(smem + 18432);  // [q 128][l] (per-wave rows)
  float  (*Os)[68] = (float (*)[68])(smem);          // epilogue [q 128][d]

  const int tid  = threadIdx.x;
  const int w    = tid >> 6;
  const int lane = tid & 63;
  const int l15  = lane & 15;
  const int g    = lane >> 4;

  const float*  qb = q  + (size_t)(b * DIMX + h * DHEAD) * HW;
  const bf16_t* kb = kt + ((size_t)(b * NHEAD + h) * LKV) * DHEAD;
  const bf16_t* vb = vt + (size_t)(b * DIMX + h * DHEAD) * LKV;

  // Q fragments (dual-use layout: A[row=l15][k=g*8+i] == B[k=g*8+i][col=l15]),
  // pre-scaled by 0.125*log2(e)
  const float QSCL = 0.18033688011112042f;
  bf16x8 qf[2][2];
#pragma unroll
  for (int rs = 0; rs < 2; ++rs) {
    const int p = p0 + w * 32 + rs * 16 + l15;
    const bool valid = p < HW;
#pragma unroll
    for (int c2 = 0; c2 < 2; ++c2)
#pragma unroll
      for (int i = 0; i < 8; ++i) {
        const int d = c2 * 32 + g * 8 + i;
        qf[rs][c2][i] = valid ? (bf16_t)(qb[(size_t)d * HW + p] * QSCL) : (bf16_t)0.f;
      }
  }

  f32x4 acc[2][4];     // O^T: acc[rs][n][r] = O[d=n*16+g*4+r][q=rs*16+l15]
  float lsum[2];       // per-lane partial sum (this lane's l-subset)
#pragma unroll
  for (int rs = 0; rs < 2; ++rs) {
    lsum[rs] = 0.f;
#pragma unroll
    for (int n = 0; n < 4; ++n) { acc[rs][n][0]=0.f; acc[rs][n][1]=0.f; acc[rs][n][2]=0.f; acc[rs][n][3]=0.f; }
  }

  for (int t = 0; t < 13; ++t) {
    const int l0 = t * 64;
    // stage K rows ([l][d], vector copy)
    {
      const int l = tid >> 2, d0 = (tid & 3) * 16;
      const int lg = l0 + l;
      if (lg < LKV) {
        const bf16_t* src = kb + (size_t)lg * DHEAD + d0;
        *(bf16x8*)&Ks[l][d0]     = *(const bf16x8*)src;
        *(bf16x8*)&Ks[l][d0 + 8] = *(const bf16x8*)(src + 8);
      } else {
        bf16x8 z;
#pragma unroll
        for (int k = 0; k < 8; ++k) z[k] = (bf16_t)0.f;
        *(bf16x8*)&Ks[l][d0] = z;
        *(bf16x8*)&Ks[l][d0 + 8] = z;
      }
    }
    // stage V rows ([d][l])
    {
      const int d = tid >> 2, lc = (tid & 3) * 16;
#pragma unroll
      for (int jj = 0; jj < 2; ++jj) {
        const int lg = l0 + lc + jj * 8;
        bf16x8 v;
        if (lg + 8 <= LKV) v = *(const bf16x8*)(vb + (size_t)d * LKV + lg);
        else {
#pragma unroll
          for (int k = 0; k < 8; ++k) v[k] = (bf16_t)0.f;
        }
        *(bf16x8*)&Vs[d][lc + jj * 8] = v;
      }
    }
    __syncthreads();

    // QK^T swapped: s[rs][n] holds S^T rows l=l0+n*16+g*4+r, col q=rs*16+l15
    f32x4 s[2][4];
    __builtin_amdgcn_s_setprio(1);
#pragma unroll
    for (int rs = 0; rs < 2; ++rs)
#pragma unroll
      for (int n = 0; n < 4; ++n) {
        f32x4 z; z[0]=0.f; z[1]=0.f; z[2]=0.f; z[3]=0.f;
        z = mfma16(*(const bf16x8*)&Ks[n * 16 + l15][g * 8],      qf[rs][0], z);
        z = mfma16(*(const bf16x8*)&Ks[n * 16 + l15][32 + g * 8], qf[rs][1], z);
        s[rs][n] = z;
      }
    __builtin_amdgcn_s_setprio(0);
    if (l0 + 64 > LKV) {
#pragma unroll
      for (int n = 0; n < 4; ++n)
#pragma unroll
        for (int r = 0; r < 4; ++r)
          if (l0 + n * 16 + g * 4 + r >= LKV) {
#pragma unroll
            for (int rs = 0; rs < 2; ++rs) s[rs][n][r] = -1e30f;
          }
    }

    // P = exp2(s); lane-local l partials; packed b64 writes to Pt[q][l]
#pragma unroll
    for (int rs = 0; rs < 2; ++rs)
#pragma unroll
      for (int n = 0; n < 4; ++n) {
        bf16x4 pk;
#pragma unroll
        for (int r = 0; r < 4; ++r) {
          const float pv = exp2f(s[rs][n][r]);
          lsum[rs] += pv;
          pk[r] = (bf16_t)pv;
        }
        *(bf16x4*)&Pt[w * 32 + rs * 16 + l15][n * 16 + g * 4] = pk;
      }

    // PV: acc[rs][n] = mfma(V^T-frag, P^T-frag) -> O^T
    __builtin_amdgcn_s_setprio(1);
#pragma unroll
    for (int c2 = 0; c2 < 2; ++c2) {
      bf16x8 vf[4];
#pragma unroll
      for (int n = 0; n < 4; ++n)
        vf[n] = *(const bf16x8*)&Vs[n * 16 + l15][c2 * 32 + g * 8];
#pragma unroll
      for (int rs = 0; rs < 2; ++rs) {
        const bf16x8 pf = *(const bf16x8*)&Pt[w * 32 + rs * 16 + l15][c2 * 32 + g * 8];
#pragma unroll
        for (int n = 0; n < 4; ++n)
          acc[rs][n] = mfma16(vf[n], pf, acc[rs][n]);
      }
    }
    __builtin_amdgcn_s_setprio(0);
    __syncthreads();
  }

  // epilogue: reduce lsum over the 4 g-groups, normalize, packed Os writes
  float inv[2];
#pragma unroll
  for (int rs = 0; rs < 2; ++rs) {
    float red = lsum[rs];
    red += __shfl_xor(red, 16);
    red += __shfl_xor(red, 32);
    inv[rs] = 1.f / red;
  }
#pragma unroll
  for (int rs = 0; rs < 2; ++rs)
#pragma unroll
    for (int n = 0; n < 4; ++n) {
      f32x4 o4;
#pragma unroll
      for (int r = 0; r < 4; ++r) o4[r] = acc[rs][n][r] * inv[rs];
      *(f32x4*)&Os[w * 32 + rs * 16 + l15][n * 16 + g * 4] = o4;
    }
  __syncthreads();
  {
    const int pr = tid >> 1, c0 = (tid & 1) * 32;
    const int p = p0 + pr;
    if (p < HW) {
      bf16_t* dst = aot + ((size_t)b * HW + p) * DIMX + h * DHEAD + c0;
#pragma unroll
      for (int jj = 0; jj < 4; ++jj) {
        bf16x8 o8;
#pragma unroll
        for (int k = 0; k < 8; ++k) o8[k] = (bf16_t)Os[pr][c0 + jj * 8 + k];
        *(bf16x8*)(dst + jj * 8) = o8;
      }
    }
  }
}

// ---------------------------------------------------------------------------
extern "C" void kernel_launch(void* const* d_in, const int* in_sizes, int n_in,
                              void* d_out, int out_size, void* d_ws, size_t ws_size,
                              hipStream_t stream) {
  const float* x       = (const float*)d_in[0];
  const float* q_w     = (const float*)d_in[1];
  const float* kv_w    = (const float*)d_in[2];
  const float* proj_w  = (const float*)d_in[3];
  const float* proj_b  = (const float*)d_in[4];
  const float* dw_w    = (const float*)d_in[5];
  const float* dw_b    = (const float*)d_in[6];
  const float* bn_w    = (const float*)d_in[7];
  const float* bn_b    = (const float*)d_in[8];
  const float* bn_mean = (const float*)d_in[9];
  const float* bn_var  = (const float*)d_in[10];
  const float* pw_w    = (const float*)d_in[11];
  float* out = (float*)d_out;

  // workspace (bytes), total ~83.3 MB
  char* ws = (char*)d_ws;
  float*  qbuf  = (float*)(ws);                       // 38,535,168 (8,384,3136) f32
  float*  offb  = (float*)(ws + 38535168);            //  9,633,792 (24,128,784) f32
  float*  gxy   = (float*)(ws + 48168960);            //    150,528
  float*  modb  = (float*)(ws + 48319488);            //     75,264
  bf16_t* ktb   = (bf16_t*)(ws + 48394752);           //  4,816,896 (8,6,784,64) bf16
  bf16_t* vtb   = (bf16_t*)(ws + 53211648);           //  4,816,896 (8,384,784) bf16
  bf16_t* xsb   = (bf16_t*)(ws + 58028544);           //  4,816,896 (24,128,784) bf16
  bf16_t* xt    = (bf16_t*)(ws + 62845440);           // 19,267,584 (8,3136,384) bf16
  bf16_t* aot   = xt;                                 // overlay: xt dead after q-proj
  bf16_t* wbf   = (bf16_t*)(ws + 82113024);           //  1,179,648 weights bf16
  bf16_t* q_wb  = wbf;
  bf16_t* kv_wb = wbf + 147456;
  bf16_t* pj_wb = wbf + 442368;

  const dim3 blk(256);
  // 0. converts
  xt_cvt<<<dim3(49, 6, 8), blk, 0, stream>>>(x, xt);
  cvt_w3<<<dim3(576), blk, 0, stream>>>(q_w, kv_w, proj_w, wbf);
  // 1. q projection (BTRANS in, fp32 out)
  gemm_mfma<false, false, true, false><<<dim3(49, 6, 8), blk, 0, stream>>>(
      q_wb, xt, nullptr, qbuf, nullptr, 384, 3136, 384);
  // 2. depthwise conv + BN + GELU
  dw_bn_gelu<<<dim3(3072), blk, 0, stream>>>(qbuf, dw_w, dw_b, bn_w, bn_b, bn_mean, bn_var, offb);
  // 3. pointwise -> offsets + (double-sigmoid) modulation -> coords
  om_grid<<<dim3(4, 24), blk, 0, stream>>>(offb, pw_w, gxy, modb);
  // 4. bilinear sample * modulation -> bf16 (c-major)
  sample_mod<<<dim3(3072), blk, 0, stream>>>(x, gxy, modb, xsb);
  // 5. kv projection -> K transposed [b,h,l,d] + V [b,c,l]
  gemm_mfma<false, false, false, true><<<dim3(13, 12, 8), blk, 0, stream>>>(
      kv_wb, xsb, nullptr, ktb, vtb, 384, 784, 768);
  // 6. attention (swapped QK^T, no-max softmax) -> aot (b,p,c) bf16
  attn_mfma<<<dim3(25, 6, 8), blk, 0, stream>>>(qbuf, ktb, vtb, aot);
  // 7. out projection (+bias, BTRANS in) -> d_out fp32
  gemm_mfma<true, false, true, false><<<dim3(49, 6, 8), blk, 0, stream>>>(
      pj_wb, aot, proj_b, out, nullptr, 384, 3136, 384);
}

// Round 8
// 220.916 us; speedup vs baseline: 4.5459x; 1.0627x over previous
//
#include <hip/hip_runtime.h>
#include <math.h>

#define DIMX 384
#define NHEAD 6
#define DHEAD 64
#define HW 3136   // 56*56
#define LKV 784   // 28*28
#define NGDX 128
#define NGRP 24   // B*3

typedef __bf16 bf16_t;
typedef __bf16 bf16x4 __attribute__((ext_vector_type(4)));
typedef __bf16 bf16x8 __attribute__((ext_vector_type(8)));
typedef float  f32x4  __attribute__((ext_vector_type(4)));

typedef unsigned int u32_g __attribute__((address_space(1)));
typedef unsigned int u32_l __attribute__((address_space(3)));

static __device__ __forceinline__ f32x4 mfma16(bf16x8 a, bf16x8 b, f32x4 c) {
  return __builtin_amdgcn_mfma_f32_16x16x32_bf16(a, b, c, 0, 0, 0);
}
// async global->LDS, 16B per lane; LDS dest = wave-uniform base + lane*16
static __device__ __forceinline__ void gload16(const void* g, void* l) {
  __builtin_amdgcn_global_load_lds((const u32_g*)g, (u32_l*)l, 16, 0, 0);
}

// ---------------------------------------------------------------------------
// x (b,c,p) fp32 -> xt (b,p,c) bf16, LDS 64x64 tile transpose
// ---------------------------------------------------------------------------
__global__ __launch_bounds__(256) void xt_cvt(
    const float* __restrict__ x, bf16_t* __restrict__ xt)
{
  const int p0 = blockIdx.x * 64, c0 = blockIdx.y * 64, b = blockIdx.z;
  __shared__ float T[64][65];
  const int tid = threadIdx.x;
  {
    const int c = tid >> 2, pc = (tid & 3) * 16;
    const float* src = x + ((size_t)b * DIMX + c0 + c) * HW + p0 + pc;
#pragma unroll
    for (int j = 0; j < 4; ++j) {
      const float4 v = *(const float4*)(src + j * 4);
      T[c][pc + j * 4 + 0] = v.x; T[c][pc + j * 4 + 1] = v.y;
      T[c][pc + j * 4 + 2] = v.z; T[c][pc + j * 4 + 3] = v.w;
    }
  }
  __syncthreads();
  {
    const int p = tid >> 2, cc = (tid & 3) * 16;
    bf16_t* dst = xt + ((size_t)b * HW + p0 + p) * DIMX + c0 + cc;
#pragma unroll
    for (int jj = 0; jj < 2; ++jj) {
      bf16x8 o;
#pragma unroll
      for (int k = 0; k < 8; ++k) o[k] = (bf16_t)T[cc + jj * 8 + k][p];
      *(bf16x8*)(dst + jj * 8) = o;
    }
  }
}

// convert the three weight matrices into one bf16 arena
__global__ __launch_bounds__(256) void cvt_w3(
    const float* __restrict__ qw, const float* __restrict__ kvw,
    const float* __restrict__ pw, bf16_t* __restrict__ dst)
{
  const int i = blockIdx.x * 256 + threadIdx.x;
  if (i >= 147456) return;
  const int e = i * 4;
  const float* src;
  int off;
  if (e < 147456)      { src = qw;  off = e; }
  else if (e < 442368) { src = kvw; off = e - 147456; }
  else                 { src = pw;  off = e - 442368; }
  const float4 v = *(const float4*)(src + off);
  bf16x4 o;
  o[0] = (bf16_t)v.x; o[1] = (bf16_t)v.y; o[2] = (bf16_t)v.z; o[3] = (bf16_t)v.w;
  *(bf16x4*)(dst + e) = o;
}

// ---------------------------------------------------------------------------
// Fast GEMM for q-proj / out-proj (all dims multiples of 64, no guards).
// out[b,o,p] = sum_c W[o,c] * in[b,p,c] (+bias). 64x64 tile, BK=64.
// Staging via global_load_lds (linear LDS) with pre-swizzled source columns;
// reads XOR-swizzled: byte = row*128 + (col ^ ((row&7)<<4)).
// grid (P/64, O/64, B), block 256.
// ---------------------------------------------------------------------------
template<bool BIAS>
__global__ __launch_bounds__(256) void gemm_qo(
    const bf16_t* __restrict__ W, const bf16_t* __restrict__ in,
    const float* __restrict__ bias, float* __restrict__ out,
    int C, int P, int O)
{
  const int b  = blockIdx.z;
  const int o0 = blockIdx.y * 64;
  const int p0 = blockIdx.x * 64;
  __shared__ __align__(16) bf16_t As[4096];   // [64 o][64 c] swizzled
  __shared__ __align__(16) bf16_t Bs[4096];   // [64 p][64 c] swizzled
  const int tid = threadIdx.x;
  const int w = tid >> 6, lane = tid & 63, l15 = lane & 15, g = lane >> 4;
  const int lrow = lane >> 3;        // 0..7 (row within 8-row chunk; == row&7)
  const int j    = lane & 7;         // 16B slot within row

  // per-thread staging sources (swizzled column)
  const bf16_t* gA = W + (size_t)(o0 + w * 16 + lrow) * C + (j ^ lrow) * 8;
  const bf16_t* gB = in + ((size_t)b * P + p0 + w * 16 + lrow) * C + (j ^ lrow) * 8;
  char* lA = (char*)As + w * 2048;
  char* lB = (char*)Bs + w * 2048;

  f32x4 acc[4];
#pragma unroll
  for (int n = 0; n < 4; ++n) { acc[n][0]=0.f; acc[n][1]=0.f; acc[n][2]=0.f; acc[n][3]=0.f; }

  for (int c0 = 0; c0 < C; c0 += 64) {
    gload16(gA + c0,         lA);
    gload16(gA + c0 + 8 * C, lA + 1024);
    gload16(gB + c0,         lB);
    gload16(gB + c0 + 8 * C, lB + 1024);
    __syncthreads();   // drains vmcnt -> tiles ready
#pragma unroll
    for (int ks = 0; ks < 2; ++ks) {
      const int cx = (ks * 64 + g * 16) ^ ((l15 & 7) << 4);
      const bf16x8 af = *(const bf16x8*)((const char*)As + (w * 16 + l15) * 128 + cx);
#pragma unroll
      for (int n = 0; n < 4; ++n) {
        const bf16x8 bfr = *(const bf16x8*)((const char*)Bs + (n * 16 + l15) * 128 + cx);
        acc[n] = mfma16(af, bfr, acc[n]);
      }
    }
    __syncthreads();
  }

  float badd[4];
#pragma unroll
  for (int r = 0; r < 4; ++r) badd[r] = BIAS ? bias[o0 + w * 16 + g * 4 + r] : 0.f;
#pragma unroll
  for (int n = 0; n < 4; ++n) {
    const int p = p0 + n * 16 + l15;
#pragma unroll
    for (int r = 0; r < 4; ++r) {
      const int o = o0 + w * 16 + g * 4 + r;
      out[((size_t)b * O + o) * P + p] = acc[n][r] + badd[r];
    }
  }
}

// ---------------------------------------------------------------------------
// bf16 MFMA GEMM (kv projection): out = W*in, in (b,c,p) transpose-scatter.
// KSPLIT epilogue: o<384 -> K transposed [b,h,l,d]; o>=384 -> V [b,c,l].
// ---------------------------------------------------------------------------
template<bool BIAS, bool OBF16, bool BTRANS, bool KSPLIT>
__global__ __launch_bounds__(256) void gemm_mfma(
    const bf16_t* __restrict__ W, const bf16_t* __restrict__ in,
    const float* __restrict__ bias, void* __restrict__ out0,
    void* __restrict__ out1, int C, int P, int O)
{
  const int b  = blockIdx.z;
  const int o0 = blockIdx.y * 64;
  const int p0 = blockIdx.x * 64;
  __shared__ __align__(16) bf16_t As[64][72];   // [o][c]
  __shared__ __align__(16) bf16_t Bs[64][72];   // [p][c]
  const int tid = threadIdx.x;
  const int w = tid >> 6, lane = tid & 63, l15 = lane & 15, g = lane >> 4;

  f32x4 acc[4];
#pragma unroll
  for (int n = 0; n < 4; ++n) { acc[n][0]=0.f; acc[n][1]=0.f; acc[n][2]=0.f; acc[n][3]=0.f; }

  for (int c0 = 0; c0 < C; c0 += 64) {
    {
      const int o = tid >> 2, cc = (tid & 3) * 16;
      const bf16_t* src = W + (size_t)(o0 + o) * C + c0 + cc;
      *(bf16x8*)&As[o][cc]     = *(const bf16x8*)src;
      *(bf16x8*)&As[o][cc + 8] = *(const bf16x8*)(src + 8);
    }
    if (BTRANS) {
      const int pp = tid >> 2, cc = (tid & 3) * 16;
      const bf16_t* src = in + ((size_t)b * P + p0 + pp) * C + c0 + cc;
      *(bf16x8*)&Bs[pp][cc]     = *(const bf16x8*)src;
      *(bf16x8*)&Bs[pp][cc + 8] = *(const bf16x8*)(src + 8);
    } else {
      const int c = tid >> 2, pp = (tid & 3) * 16;
      const bf16_t* src = in + ((size_t)b * C + c0 + c) * P + p0 + pp;
#pragma unroll
      for (int jj = 0; jj < 2; ++jj) {
        bf16x8 v;
        if (p0 + pp + jj * 8 + 8 <= P) v = *(const bf16x8*)(src + jj * 8);
        else {
#pragma unroll
          for (int k = 0; k < 8; ++k) v[k] = (bf16_t)0.f;
        }
#pragma unroll
        for (int k = 0; k < 8; ++k) Bs[pp + jj * 8 + k][c] = v[k];
      }
    }
    __syncthreads();
#pragma unroll
    for (int ks = 0; ks < 2; ++ks) {
      const bf16x8 af = *(const bf16x8*)&As[w * 16 + l15][ks * 32 + g * 8];
#pragma unroll
      for (int n = 0; n < 4; ++n) {
        const bf16x8 bfr = *(const bf16x8*)&Bs[n * 16 + l15][ks * 32 + g * 8];
        acc[n] = mfma16(af, bfr, acc[n]);
      }
    }
    __syncthreads();
  }

  if (KSPLIT) {
    if (blockIdx.y < 6) {
      const int h = blockIdx.y;
      bf16_t* kt = (bf16_t*)out0;
#pragma unroll
      for (int n = 0; n < 4; ++n) {
        const int l = p0 + n * 16 + l15;
        if (l < P) {
          bf16x4 kq;
#pragma unroll
          for (int r = 0; r < 4; ++r) kq[r] = (bf16_t)acc[n][r];
          *(bf16x4*)&kt[(((size_t)b * NHEAD + h) * LKV + l) * DHEAD + w * 16 + g * 4] = kq;
        }
      }
    } else {
      bf16_t* vt = (bf16_t*)out1;
#pragma unroll
      for (int n = 0; n < 4; ++n) {
        const int p = p0 + n * 16 + l15;
        if (p < P) {
#pragma unroll
          for (int r = 0; r < 4; ++r) {
            const int c = o0 - DIMX + w * 16 + g * 4 + r;
            vt[((size_t)b * DIMX + c) * LKV + p] = (bf16_t)acc[n][r];
          }
        }
      }
    }
    return;
  }

  float badd[4];
#pragma unroll
  for (int r = 0; r < 4; ++r) badd[r] = BIAS ? bias[o0 + w * 16 + g * 4 + r] : 0.f;
#pragma unroll
  for (int n = 0; n < 4; ++n) {
    const int p = p0 + n * 16 + l15;
    if (p < P) {
#pragma unroll
      for (int r = 0; r < 4; ++r) {
        const int o = o0 + w * 16 + g * 4 + r;
        const float v = acc[n][r] + badd[r];
        if (OBF16) ((bf16_t*)out0)[((size_t)b * O + o) * P + p] = (bf16_t)v;
        else       ((float*)out0)[((size_t)b * O + o) * P + p] = v;
      }
    }
  }
}

// ---------------------------------------------------------------------------
// Depthwise 5x5 stride-2 conv + bias + BN + exact GELU (fp32)
// ---------------------------------------------------------------------------
__global__ __launch_bounds__(256) void dw_bn_gelu(
    const float* __restrict__ q, const float* __restrict__ dw_w,
    const float* __restrict__ dw_b, const float* __restrict__ bn_w,
    const float* __restrict__ bn_b, const float* __restrict__ bn_mean,
    const float* __restrict__ bn_var, float* __restrict__ off)
{
  const int nc = blockIdx.x;
  const int c  = nc & 127;
  const float* plane = q + (size_t)nc * HW;
  float w[25];
#pragma unroll
  for (int k = 0; k < 25; ++k) w[k] = dw_w[c * 25 + k];
  const float beta  = dw_b[c];
  const float scale = bn_w[c] * rsqrtf(bn_var[c] + 1e-6f);
  const float shift = bn_b[c] - bn_mean[c] * scale;

  for (int p = threadIdx.x; p < LKV; p += 256) {
    const int oy = p / 28, ox = p % 28;
    const int iy0 = oy * 2 - 2, ix0 = ox * 2 - 2;
    float s = 0.f;
#pragma unroll
    for (int ky = 0; ky < 5; ++ky) {
      const int y = iy0 + ky;
      if ((unsigned)y >= 56u) continue;
#pragma unroll
      for (int kx = 0; kx < 5; ++kx) {
        const int x = ix0 + kx;
        if ((unsigned)x >= 56u) continue;
        s += plane[y * 56 + x] * w[ky * 5 + kx];
      }
    }
    s = (s + beta) * scale + shift;
    const float g = 0.5f * s * (1.f + erff(s * 0.70710678118654752f));
    off[(size_t)nc * LKV + p] = g;
  }
}

// ---------------------------------------------------------------------------
// Pointwise (3,128) -> offsets / double-sigmoid modulation -> sample coords
// ---------------------------------------------------------------------------
__global__ __launch_bounds__(256) void om_grid(
    const float* __restrict__ off, const float* __restrict__ pw_w,
    float* __restrict__ gxy, float* __restrict__ modb)
{
  const int n = blockIdx.y;
  const int p = blockIdx.x * 256 + threadIdx.x;
  if (p >= LKV) return;
  const float* base = off + (size_t)n * NGDX * LKV + p;
  float s0 = 0.f, s1 = 0.f, s2 = 0.f;
  for (int c = 0; c < NGDX; ++c) {
    const float v = base[(size_t)c * LKV];
    s0 += v * pw_w[c];
    s1 += v * pw_w[128 + c];
    s2 += v * pw_w[256 + c];
  }
  const float sig1 = 1.f / (1.f + expf(-s2));
  const float mod  = 1.f / (1.f + expf(-sig1));   // double sigmoid (per reference)
  const float offy = tanhf(s0) * (2.f / 28.f);
  const float offx = tanhf(s1) * (2.f / 28.f);
  const int i = p / 28, j = p % 28;
  const float refy = ((i + 0.5f) / 28.f) * 2.f - 1.f;
  const float refx = ((j + 0.5f) / 28.f) * 2.f - 1.f;
  const float gy = (offy + refy + 1.f) * 0.5f * 55.f;
  const float gx = (offx + refx + 1.f) * 0.5f * 55.f;
  gxy[((size_t)n * LKV + p) * 2 + 0] = gx;
  gxy[((size_t)n * LKV + p) * 2 + 1] = gy;
  modb[(size_t)n * LKV + p] = mod;
}

// ---------------------------------------------------------------------------
// Bilinear sample * modulation -> bf16 (c-major, feeds kv GEMM scatter path)
// ---------------------------------------------------------------------------
__global__ __launch_bounds__(256) void sample_mod(
    const float* __restrict__ x, const float* __restrict__ gxy,
    const float* __restrict__ modb, bf16_t* __restrict__ xs)
{
  const int nc = blockIdx.x;
  const int n  = nc >> 7;
  const float* img = x + (size_t)nc * HW;
  for (int p = threadIdx.x; p < LKV; p += 256) {
    const float gx = gxy[((size_t)n * LKV + p) * 2 + 0];
    const float gy = gxy[((size_t)n * LKV + p) * 2 + 1];
    const float x0f = floorf(gx), y0f = floorf(gy);
    const float wx1 = gx - x0f, wy1 = gy - y0f;
    const float wx0 = (x0f + 1.f) - gx, wy0 = (y0f + 1.f) - gy;
    const int ix0 = (int)x0f, iy0 = (int)y0f;
    const int ix1 = ix0 + 1,  iy1 = iy0 + 1;
    const bool vx0 = (ix0 >= 0) && (ix0 < 56), vx1 = (ix1 >= 0) && (ix1 < 56);
    const bool vy0 = (iy0 >= 0) && (iy0 < 56), vy1 = (iy1 >= 0) && (iy1 < 56);
    const int cx0 = min(max(ix0, 0), 55), cx1 = min(max(ix1, 0), 55);
    const int cy0 = min(max(iy0, 0), 55), cy1 = min(max(iy1, 0), 55);
    const float f00 = (vy0 && vx0) ? img[cy0 * 56 + cx0] : 0.f;
    const float f10 = (vy1 && vx0) ? img[cy1 * 56 + cx0] : 0.f;
    const float f01 = (vy0 && vx1) ? img[cy0 * 56 + cx1] : 0.f;
    const float f11 = (vy1 && vx1) ? img[cy1 * 56 + cx1] : 0.f;
    const float v = f00 * (wx0 * wy0) + f10 * (wx0 * wy1)
                  + f01 * (wx1 * wy0) + f11 * (wx1 * wy1);
    xs[(size_t)nc * LKV + p] = (bf16_t)(v * modb[(size_t)n * LKV + p]);
  }
}

// ---------------------------------------------------------------------------
// bf16 MFMA attention, swapped QK^T + no-max softmax.
// K/V staged via global_load_lds into linear swizzled LDS tiles.
// grid (25, 6, 8), block 256 (4 waves x 32 q-rows). Output aot (b,p,c) bf16.
// ---------------------------------------------------------------------------
__global__ __launch_bounds__(256) void attn_mfma(
    const float* __restrict__ q, const bf16_t* __restrict__ kt,
    const bf16_t* __restrict__ vt, bf16_t* __restrict__ aot)
{
  const int p0 = blockIdx.x * 128;
  const int h  = blockIdx.y;
  const int b  = blockIdx.z;

  __shared__ __align__(16) char smem[34816];
  // Ks: [l 64][128B] swizzled, at 0 (8KB). Vs: [d 64][128B] swizzled, at 8192.
  bf16_t (*Pt)[72] = (bf16_t(*)[72])(smem + 16384);  // [q 128][l] per-wave rows
  float  (*Os)[68] = (float (*)[68])(smem);          // epilogue reuse [q 128][d]

  const int tid  = threadIdx.x;
  const int w    = tid >> 6;
  const int lane = tid & 63;
  const int l15  = lane & 15;
  const int g    = lane >> 4;
  const int lrow = lane >> 3;   // 0..7
  const int j    = lane & 7;

  const float*  qb = q  + (size_t)(b * DIMX + h * DHEAD) * HW;
  const bf16_t* kb = kt + ((size_t)(b * NHEAD + h) * LKV) * DHEAD;
  const bf16_t* vb = vt + (size_t)(b * DIMX + h * DHEAD) * LKV;

  // staging pointers: K rows l (64 d each), V rows d (64 l each)
  const bf16_t* gK = kb + (size_t)(w * 16 + lrow) * DHEAD + (j ^ lrow) * 8;
  const bf16_t* gV = vb + (size_t)(w * 16 + lrow) * LKV + (j ^ lrow) * 8;
  char* lK = smem + w * 2048;
  char* lV = smem + 8192 + w * 2048;

  // Q fragments (dual-use layout), pre-scaled by 0.125*log2(e)
  const float QSCL = 0.18033688011112042f;
  bf16x8 qf[2][2];
#pragma unroll
  for (int rs = 0; rs < 2; ++rs) {
    const int p = p0 + w * 32 + rs * 16 + l15;
    const bool valid = p < HW;
#pragma unroll
    for (int c2 = 0; c2 < 2; ++c2)
#pragma unroll
      for (int i = 0; i < 8; ++i) {
        const int d = c2 * 32 + g * 8 + i;
        qf[rs][c2][i] = valid ? (bf16_t)(qb[(size_t)d * HW + p] * QSCL) : (bf16_t)0.f;
      }
  }

  f32x4 acc[2][4];     // O^T: acc[rs][n][r] = O[d=n*16+g*4+r][q=rs*16+l15]
  float lsum[2];
#pragma unroll
  for (int rs = 0; rs < 2; ++rs) {
    lsum[rs] = 0.f;
#pragma unroll
    for (int n = 0; n < 4; ++n) { acc[rs][n][0]=0.f; acc[rs][n][1]=0.f; acc[rs][n][2]=0.f; acc[rs][n][3]=0.f; }
  }

  for (int t = 0; t < 13; ++t) {
    const int l0 = t * 64;
    // stage K tile (rows l0..l0+63 of [l][d]) and V tile ([d][l0..l0+63])
    gload16(gK + (size_t)l0 * DHEAD,                lK);
    gload16(gK + (size_t)(l0 + 8) * DHEAD,          lK + 1024);
    gload16(gV + l0,                                lV);
    gload16(gV + (size_t)8 * LKV + l0,              lV + 1024);
    __syncthreads();

    // QK^T swapped: s[rs][n] holds S^T rows l=l0+n*16+g*4+r, col q=rs*16+l15
    f32x4 s[2][4];
    __builtin_amdgcn_s_setprio(1);
#pragma unroll
    for (int n = 0; n < 4; ++n) {
      const int row = n * 16 + l15;
      const int cx0 = (g * 16) ^ ((l15 & 7) << 4);
      const int cx1 = (64 + g * 16) ^ ((l15 & 7) << 4);
      const bf16x8 k0 = *(const bf16x8*)(smem + row * 128 + cx0);
      const bf16x8 k1 = *(const bf16x8*)(smem + row * 128 + cx1);
#pragma unroll
      for (int rs = 0; rs < 2; ++rs) {
        f32x4 z; z[0]=0.f; z[1]=0.f; z[2]=0.f; z[3]=0.f;
        z = mfma16(k0, qf[rs][0], z);
        z = mfma16(k1, qf[rs][1], z);
        s[rs][n] = z;
      }
    }
    __builtin_amdgcn_s_setprio(0);
    if (l0 + 64 > LKV) {
#pragma unroll
      for (int n = 0; n < 4; ++n)
#pragma unroll
        for (int r = 0; r < 4; ++r)
          if (l0 + n * 16 + g * 4 + r >= LKV) {
#pragma unroll
            for (int rs = 0; rs < 2; ++rs) s[rs][n][r] = -1e30f;
          }
    }

    // P = exp2(s); lane-local l partials; packed b64 writes to Pt[q][l]
#pragma unroll
    for (int rs = 0; rs < 2; ++rs)
#pragma unroll
      for (int n = 0; n < 4; ++n) {
        bf16x4 pk;
#pragma unroll
        for (int r = 0; r < 4; ++r) {
          const float pv = exp2f(s[rs][n][r]);
          lsum[rs] += pv;
          pk[r] = (bf16_t)pv;
        }
        *(bf16x4*)&Pt[w * 32 + rs * 16 + l15][n * 16 + g * 4] = pk;
      }

    // PV: acc[rs][n] = mfma(V^T-frag, P^T-frag) -> O^T
    __builtin_amdgcn_s_setprio(1);
#pragma unroll
    for (int c2 = 0; c2 < 2; ++c2) {
      bf16x8 vf[4];
#pragma unroll
      for (int n = 0; n < 4; ++n) {
        const int row = n * 16 + l15;
        const int cx = (c2 * 64 + g * 16) ^ ((l15 & 7) << 4);
        vf[n] = *(const bf16x8*)(smem + 8192 + row * 128 + cx);
      }
#pragma unroll
      for (int rs = 0; rs < 2; ++rs) {
        const bf16x8 pf = *(const bf16x8*)&Pt[w * 32 + rs * 16 + l15][c2 * 32 + g * 8];
#pragma unroll
        for (int n = 0; n < 4; ++n)
          acc[rs][n] = mfma16(vf[n], pf, acc[rs][n]);
      }
    }
    __builtin_amdgcn_s_setprio(0);
    __syncthreads();
  }

  // epilogue: reduce lsum over the 4 g-groups, normalize, packed Os writes
  float inv[2];
#pragma unroll
  for (int rs = 0; rs < 2; ++rs) {
    float red = lsum[rs];
    red += __shfl_xor(red, 16);
    red += __shfl_xor(red, 32);
    inv[rs] = 1.f / red;
  }
#pragma unroll
  for (int rs = 0; rs < 2; ++rs)
#pragma unroll
    for (int n = 0; n < 4; ++n) {
      f32x4 o4;
#pragma unroll
      for (int r = 0; r < 4; ++r) o4[r] = acc[rs][n][r] * inv[rs];
      *(f32x4*)&Os[w * 32 + rs * 16 + l15][n * 16 + g * 4] = o4;
    }
  __syncthreads();
  {
    const int pr = tid >> 1, c0 = (tid & 1) * 32;
    const int p = p0 + pr;
    if (p < HW) {
      bf16_t* dst = aot + ((size_t)b * HW + p) * DIMX + h * DHEAD + c0;
#pragma unroll
      for (int jj = 0; jj < 4; ++jj) {
        bf16x8 o8;
#pragma unroll
        for (int k = 0; k < 8; ++k) o8[k] = (bf16_t)Os[pr][c0 + jj * 8 + k];
        *(bf16x8*)(dst + jj * 8) = o8;
      }
    }
  }
}

// ---------------------------------------------------------------------------
extern "C" void kernel_launch(void* const* d_in, const int* in_sizes, int n_in,
                              void* d_out, int out_size, void* d_ws, size_t ws_size,
                              hipStream_t stream) {
  const float* x       = (const float*)d_in[0];
  const float* q_w     = (const float*)d_in[1];
  const float* kv_w    = (const float*)d_in[2];
  const float* proj_w  = (const float*)d_in[3];
  const float* proj_b  = (const float*)d_in[4];
  const float* dw_w    = (const float*)d_in[5];
  const float* dw_b    = (const float*)d_in[6];
  const float* bn_w    = (const float*)d_in[7];
  const float* bn_b    = (const float*)d_in[8];
  const float* bn_mean = (const float*)d_in[9];
  const float* bn_var  = (const float*)d_in[10];
  const float* pw_w    = (const float*)d_in[11];
  float* out = (float*)d_out;

  // workspace (bytes), total ~83.3 MB
  char* ws = (char*)d_ws;
  float*  qbuf  = (float*)(ws);                       // 38,535,168 (8,384,3136) f32
  float*  offb  = (float*)(ws + 38535168);            //  9,633,792 (24,128,784) f32
  float*  gxy   = (float*)(ws + 48168960);            //    150,528
  float*  modb  = (float*)(ws + 48319488);            //     75,264
  bf16_t* ktb   = (bf16_t*)(ws + 48394752);           //  4,816,896 (8,6,784,64) bf16
  bf16_t* vtb   = (bf16_t*)(ws + 53211648);           //  4,816,896 (8,384,784) bf16
  bf16_t* xsb   = (bf16_t*)(ws + 58028544);           //  4,816,896 (24,128,784) bf16
  bf16_t* xt    = (bf16_t*)(ws + 62845440);           // 19,267,584 (8,3136,384) bf16
  bf16_t* aot   = xt;                                 // overlay: xt dead after q-proj
  bf16_t* wbf   = (bf16_t*)(ws + 82113024);           //  1,179,648 weights bf16
  bf16_t* q_wb  = wbf;
  bf16_t* kv_wb = wbf + 147456;
  bf16_t* pj_wb = wbf + 442368;

  const dim3 blk(256);
  // 0. converts
  xt_cvt<<<dim3(49, 6, 8), blk, 0, stream>>>(x, xt);
  cvt_w3<<<dim3(576), blk, 0, stream>>>(q_w, kv_w, proj_w, wbf);
  // 1. q projection (fast path, fp32 out)
  gemm_qo<false><<<dim3(49, 6, 8), blk, 0, stream>>>(q_wb, xt, nullptr, qbuf, 384, 3136, 384);
  // 2. depthwise conv + BN + GELU
  dw_bn_gelu<<<dim3(3072), blk, 0, stream>>>(qbuf, dw_w, dw_b, bn_w, bn_b, bn_mean, bn_var, offb);
  // 3. pointwise -> offsets + (double-sigmoid) modulation -> coords
  om_grid<<<dim3(4, 24), blk, 0, stream>>>(offb, pw_w, gxy, modb);
  // 4. bilinear sample * modulation -> bf16 (c-major)
  sample_mod<<<dim3(3072), blk, 0, stream>>>(x, gxy, modb, xsb);
  // 5. kv projection -> K transposed [b,h,l,d] + V [b,c,l]
  gemm_mfma<false, false, false, true><<<dim3(13, 12, 8), blk, 0, stream>>>(
      kv_wb, xsb, nullptr, ktb, vtb, 384, 784, 768);
  // 6. attention (swapped QK^T, no-max softmax) -> aot (b,p,c) bf16
  attn_mfma<<<dim3(25, 6, 8), blk, 0, stream>>>(qbuf, ktb, vtb, aot);
  // 7. out projection (+bias, fast path) -> d_out fp32
  gemm_qo<true><<<dim3(49, 6, 8), blk, 0, stream>>>(pj_wb, aot, proj_b, out, 384, 3136, 384);
}

// Round 9
// 209.949 us; speedup vs baseline: 4.7834x; 1.0522x over previous
//
#include <hip/hip_runtime.h>
#include <math.h>

#define DIMX 384
#define NHEAD 6
#define DHEAD 64
#define HW 3136   // 56*56
#define LKV 784   // 28*28
#define NGDX 128
#define NGRP 24   // B*3

typedef __bf16 bf16_t;
typedef __bf16 bf16x4 __attribute__((ext_vector_type(4)));
typedef __bf16 bf16x8 __attribute__((ext_vector_type(8)));
typedef float  f32x4  __attribute__((ext_vector_type(4)));

typedef unsigned int u32_g __attribute__((address_space(1)));
typedef unsigned int u32_l __attribute__((address_space(3)));

static __device__ __forceinline__ f32x4 mfma16(bf16x8 a, bf16x8 b, f32x4 c) {
  return __builtin_amdgcn_mfma_f32_16x16x32_bf16(a, b, c, 0, 0, 0);
}
// async global->LDS, 16B per lane; LDS dest = wave-uniform base + lane*16
static __device__ __forceinline__ void gload16(const void* g, void* l) {
  __builtin_amdgcn_global_load_lds((const u32_g*)g, (u32_l*)l, 16, 0, 0);
}

// ---------------------------------------------------------------------------
// x (b,c,p) fp32 -> xt (b,p,c) bf16, LDS 64x64 tile transpose
// ---------------------------------------------------------------------------
__global__ __launch_bounds__(256) void xt_cvt(
    const float* __restrict__ x, bf16_t* __restrict__ xt)
{
  const int p0 = blockIdx.x * 64, c0 = blockIdx.y * 64, b = blockIdx.z;
  __shared__ float T[64][65];
  const int tid = threadIdx.x;
  {
    const int c = tid >> 2, pc = (tid & 3) * 16;
    const float* src = x + ((size_t)b * DIMX + c0 + c) * HW + p0 + pc;
#pragma unroll
    for (int j = 0; j < 4; ++j) {
      const float4 v = *(const float4*)(src + j * 4);
      T[c][pc + j * 4 + 0] = v.x; T[c][pc + j * 4 + 1] = v.y;
      T[c][pc + j * 4 + 2] = v.z; T[c][pc + j * 4 + 3] = v.w;
    }
  }
  __syncthreads();
  {
    const int p = tid >> 2, cc = (tid & 3) * 16;
    bf16_t* dst = xt + ((size_t)b * HW + p0 + p) * DIMX + c0 + cc;
#pragma unroll
    for (int jj = 0; jj < 2; ++jj) {
      bf16x8 o;
#pragma unroll
      for (int k = 0; k < 8; ++k) o[k] = (bf16_t)T[cc + jj * 8 + k][p];
      *(bf16x8*)(dst + jj * 8) = o;
    }
  }
}

// convert the three weight matrices into one bf16 arena
__global__ __launch_bounds__(256) void cvt_w3(
    const float* __restrict__ qw, const float* __restrict__ kvw,
    const float* __restrict__ pw, bf16_t* __restrict__ dst)
{
  const int i = blockIdx.x * 256 + threadIdx.x;
  if (i >= 147456) return;
  const int e = i * 4;
  const float* src;
  int off;
  if (e < 147456)      { src = qw;  off = e; }
  else if (e < 442368) { src = kvw; off = e - 147456; }
  else                 { src = pw;  off = e - 442368; }
  const float4 v = *(const float4*)(src + off);
  bf16x4 o;
  o[0] = (bf16_t)v.x; o[1] = (bf16_t)v.y; o[2] = (bf16_t)v.z; o[3] = (bf16_t)v.w;
  *(bf16x4*)(dst + e) = o;
}

// ---------------------------------------------------------------------------
// Fast GEMM for q-proj / out-proj (all dims multiples of 64, no guards).
// out[b,o,p] = sum_c W[o,c] * in[b,p,c] (+bias). 64x64 tile, BK=64.
// Staging via global_load_lds (linear LDS) with pre-swizzled source columns;
// reads XOR-swizzled: byte = row*128 + (col ^ ((row&7)<<4)).
// ---------------------------------------------------------------------------
template<bool BIAS, bool OBF16>
__global__ __launch_bounds__(256) void gemm_qo(
    const bf16_t* __restrict__ W, const bf16_t* __restrict__ in,
    const float* __restrict__ bias, void* __restrict__ outv,
    int C, int P, int O)
{
  const int b  = blockIdx.z;
  const int o0 = blockIdx.y * 64;
  const int p0 = blockIdx.x * 64;
  __shared__ __align__(16) bf16_t As[4096];   // [64 o][64 c] swizzled
  __shared__ __align__(16) bf16_t Bs[4096];   // [64 p][64 c] swizzled
  const int tid = threadIdx.x;
  const int w = tid >> 6, lane = tid & 63, l15 = lane & 15, g = lane >> 4;
  const int lrow = lane >> 3;        // 0..7
  const int j    = lane & 7;

  const bf16_t* gA = W + (size_t)(o0 + w * 16 + lrow) * C + (j ^ lrow) * 8;
  const bf16_t* gB = in + ((size_t)b * P + p0 + w * 16 + lrow) * C + (j ^ lrow) * 8;
  char* lA = (char*)As + w * 2048;
  char* lB = (char*)Bs + w * 2048;

  f32x4 acc[4];
#pragma unroll
  for (int n = 0; n < 4; ++n) { acc[n][0]=0.f; acc[n][1]=0.f; acc[n][2]=0.f; acc[n][3]=0.f; }

  for (int c0 = 0; c0 < C; c0 += 64) {
    gload16(gA + c0,         lA);
    gload16(gA + c0 + 8 * C, lA + 1024);
    gload16(gB + c0,         lB);
    gload16(gB + c0 + 8 * C, lB + 1024);
    __syncthreads();
#pragma unroll
    for (int ks = 0; ks < 2; ++ks) {
      const int cx = (ks * 64 + g * 16) ^ ((l15 & 7) << 4);
      const bf16x8 af = *(const bf16x8*)((const char*)As + (w * 16 + l15) * 128 + cx);
#pragma unroll
      for (int n = 0; n < 4; ++n) {
        const bf16x8 bfr = *(const bf16x8*)((const char*)Bs + (n * 16 + l15) * 128 + cx);
        acc[n] = mfma16(af, bfr, acc[n]);
      }
    }
    __syncthreads();
  }

  float badd[4];
#pragma unroll
  for (int r = 0; r < 4; ++r) badd[r] = BIAS ? bias[o0 + w * 16 + g * 4 + r] : 0.f;
#pragma unroll
  for (int n = 0; n < 4; ++n) {
    const int p = p0 + n * 16 + l15;
#pragma unroll
    for (int r = 0; r < 4; ++r) {
      const int o = o0 + w * 16 + g * 4 + r;
      const float v = acc[n][r] + badd[r];
      if (OBF16) ((bf16_t*)outv)[((size_t)b * O + o) * P + p] = (bf16_t)v;
      else       ((float*)outv)[((size_t)b * O + o) * P + p] = v;
    }
  }
}

// ---------------------------------------------------------------------------
// bf16 MFMA GEMM (kv projection): in (b,c,p) transpose-scatter staging.
// KSPLIT epilogue: o<384 -> K transposed [b,h,l,d]; o>=384 -> V [b,c,l].
// ---------------------------------------------------------------------------
__global__ __launch_bounds__(256) void gemm_kv(
    const bf16_t* __restrict__ W, const bf16_t* __restrict__ in,
    bf16_t* __restrict__ ktb, bf16_t* __restrict__ vtb, int C, int P, int O)
{
  const int b  = blockIdx.z;
  const int o0 = blockIdx.y * 64;
  const int p0 = blockIdx.x * 64;
  __shared__ __align__(16) bf16_t As[64][72];   // [o][c]
  __shared__ __align__(16) bf16_t Bs[64][72];   // [p][c]
  const int tid = threadIdx.x;
  const int w = tid >> 6, lane = tid & 63, l15 = lane & 15, g = lane >> 4;

  f32x4 acc[4];
#pragma unroll
  for (int n = 0; n < 4; ++n) { acc[n][0]=0.f; acc[n][1]=0.f; acc[n][2]=0.f; acc[n][3]=0.f; }

  for (int c0 = 0; c0 < C; c0 += 64) {
    {
      const int o = tid >> 2, cc = (tid & 3) * 16;
      const bf16_t* src = W + (size_t)(o0 + o) * C + c0 + cc;
      *(bf16x8*)&As[o][cc]     = *(const bf16x8*)src;
      *(bf16x8*)&As[o][cc + 8] = *(const bf16x8*)(src + 8);
    }
    {
      const int c = tid >> 2, pp = (tid & 3) * 16;
      const bf16_t* src = in + ((size_t)b * C + c0 + c) * P + p0 + pp;
#pragma unroll
      for (int jj = 0; jj < 2; ++jj) {
        bf16x8 v;
        if (p0 + pp + jj * 8 + 8 <= P) v = *(const bf16x8*)(src + jj * 8);
        else {
#pragma unroll
          for (int k = 0; k < 8; ++k) v[k] = (bf16_t)0.f;
        }
#pragma unroll
        for (int k = 0; k < 8; ++k) Bs[pp + jj * 8 + k][c] = v[k];
      }
    }
    __syncthreads();
#pragma unroll
    for (int ks = 0; ks < 2; ++ks) {
      const bf16x8 af = *(const bf16x8*)&As[w * 16 + l15][ks * 32 + g * 8];
#pragma unroll
      for (int n = 0; n < 4; ++n) {
        const bf16x8 bfr = *(const bf16x8*)&Bs[n * 16 + l15][ks * 32 + g * 8];
        acc[n] = mfma16(af, bfr, acc[n]);
      }
    }
    __syncthreads();
  }

  if (blockIdx.y < 6) {
    const int h = blockIdx.y;
#pragma unroll
    for (int n = 0; n < 4; ++n) {
      const int l = p0 + n * 16 + l15;
      if (l < P) {
        bf16x4 kq;
#pragma unroll
        for (int r = 0; r < 4; ++r) kq[r] = (bf16_t)acc[n][r];
        *(bf16x4*)&ktb[(((size_t)b * NHEAD + h) * LKV + l) * DHEAD + w * 16 + g * 4] = kq;
      }
    }
  } else {
#pragma unroll
    for (int n = 0; n < 4; ++n) {
      const int p = p0 + n * 16 + l15;
      if (p < P) {
#pragma unroll
        for (int r = 0; r < 4; ++r) {
          const int c = o0 - DIMX + w * 16 + g * 4 + r;
          vtb[((size_t)b * DIMX + c) * LKV + p] = (bf16_t)acc[n][r];
        }
      }
    }
  }
}

// ---------------------------------------------------------------------------
// Depthwise 5x5 stride-2 conv + bias + BN + exact GELU (bf16 in, fp32 out)
// ---------------------------------------------------------------------------
__global__ __launch_bounds__(256) void dw_bn_gelu(
    const bf16_t* __restrict__ q, const float* __restrict__ dw_w,
    const float* __restrict__ dw_b, const float* __restrict__ bn_w,
    const float* __restrict__ bn_b, const float* __restrict__ bn_mean,
    const float* __restrict__ bn_var, float* __restrict__ off)
{
  const int nc = blockIdx.x;
  const int c  = nc & 127;
  const bf16_t* plane = q + (size_t)nc * HW;
  float w[25];
#pragma unroll
  for (int k = 0; k < 25; ++k) w[k] = dw_w[c * 25 + k];
  const float beta  = dw_b[c];
  const float scale = bn_w[c] * rsqrtf(bn_var[c] + 1e-6f);
  const float shift = bn_b[c] - bn_mean[c] * scale;

  for (int p = threadIdx.x; p < LKV; p += 256) {
    const int oy = p / 28, ox = p % 28;
    const int iy0 = oy * 2 - 2, ix0 = ox * 2 - 2;
    float s = 0.f;
#pragma unroll
    for (int ky = 0; ky < 5; ++ky) {
      const int y = iy0 + ky;
      if ((unsigned)y >= 56u) continue;
#pragma unroll
      for (int kx = 0; kx < 5; ++kx) {
        const int x = ix0 + kx;
        if ((unsigned)x >= 56u) continue;
        s += (float)plane[y * 56 + x] * w[ky * 5 + kx];
      }
    }
    s = (s + beta) * scale + shift;
    const float g = 0.5f * s * (1.f + erff(s * 0.70710678118654752f));
    off[(size_t)nc * LKV + p] = g;
  }
}

// ---------------------------------------------------------------------------
// Pointwise (3,128) -> offsets / double-sigmoid modulation -> sample coords
// ---------------------------------------------------------------------------
__global__ __launch_bounds__(256) void om_grid(
    const float* __restrict__ off, const float* __restrict__ pw_w,
    float* __restrict__ gxy, float* __restrict__ modb)
{
  const int n = blockIdx.y;
  const int p = blockIdx.x * 256 + threadIdx.x;
  if (p >= LKV) return;
  const float* base = off + (size_t)n * NGDX * LKV + p;
  float s0 = 0.f, s1 = 0.f, s2 = 0.f;
  for (int c = 0; c < NGDX; ++c) {
    const float v = base[(size_t)c * LKV];
    s0 += v * pw_w[c];
    s1 += v * pw_w[128 + c];
    s2 += v * pw_w[256 + c];
  }
  const float sig1 = 1.f / (1.f + expf(-s2));
  const float mod  = 1.f / (1.f + expf(-sig1));   // double sigmoid (per reference)
  const float offy = tanhf(s0) * (2.f / 28.f);
  const float offx = tanhf(s1) * (2.f / 28.f);
  const int i = p / 28, j = p % 28;
  const float refy = ((i + 0.5f) / 28.f) * 2.f - 1.f;
  const float refx = ((j + 0.5f) / 28.f) * 2.f - 1.f;
  const float gy = (offy + refy + 1.f) * 0.5f * 55.f;
  const float gx = (offx + refx + 1.f) * 0.5f * 55.f;
  gxy[((size_t)n * LKV + p) * 2 + 0] = gx;
  gxy[((size_t)n * LKV + p) * 2 + 1] = gy;
  modb[(size_t)n * LKV + p] = mod;
}

// ---------------------------------------------------------------------------
// Bilinear sample * modulation -> bf16 (c-major, feeds kv GEMM scatter path)
// ---------------------------------------------------------------------------
__global__ __launch_bounds__(256) void sample_mod(
    const float* __restrict__ x, const float* __restrict__ gxy,
    const float* __restrict__ modb, bf16_t* __restrict__ xs)
{
  const int nc = blockIdx.x;
  const int n  = nc >> 7;
  const float* img = x + (size_t)nc * HW;
  for (int p = threadIdx.x; p < LKV; p += 256) {
    const float gx = gxy[((size_t)n * LKV + p) * 2 + 0];
    const float gy = gxy[((size_t)n * LKV + p) * 2 + 1];
    const float x0f = floorf(gx), y0f = floorf(gy);
    const float wx1 = gx - x0f, wy1 = gy - y0f;
    const float wx0 = (x0f + 1.f) - gx, wy0 = (y0f + 1.f) - gy;
    const int ix0 = (int)x0f, iy0 = (int)y0f;
    const int ix1 = ix0 + 1,  iy1 = iy0 + 1;
    const bool vx0 = (ix0 >= 0) && (ix0 < 56), vx1 = (ix1 >= 0) && (ix1 < 56);
    const bool vy0 = (iy0 >= 0) && (iy0 < 56), vy1 = (iy1 >= 0) && (iy1 < 56);
    const int cx0 = min(max(ix0, 0), 55), cx1 = min(max(ix1, 0), 55);
    const int cy0 = min(max(iy0, 0), 55), cy1 = min(max(iy1, 0), 55);
    const float f00 = (vy0 && vx0) ? img[cy0 * 56 + cx0] : 0.f;
    const float f10 = (vy1 && vx0) ? img[cy1 * 56 + cx0] : 0.f;
    const float f01 = (vy0 && vx1) ? img[cy0 * 56 + cx1] : 0.f;
    const float f11 = (vy1 && vx1) ? img[cy1 * 56 + cx1] : 0.f;
    const float v = f00 * (wx0 * wy0) + f10 * (wx0 * wy1)
                  + f01 * (wx1 * wy0) + f11 * (wx1 * wy1);
    xs[(size_t)nc * LKV + p] = (bf16_t)(v * modb[(size_t)n * LKV + p]);
  }
}

// ---------------------------------------------------------------------------
// bf16 MFMA attention: swapped QK^T, no-max softmax, double-buffered K/V
// (1 barrier/tile), lsum via ones-MFMA (no scalar adds, no shuffle reduce).
// grid (25, 6, 8), block 256 (4 waves x 32 q-rows). Output aot (b,p,c) bf16.
// LDS: K0 0..8K | V0 8K..16K | K1 16K..24K | V1 24K..32K | Pt 32K..50K
// ---------------------------------------------------------------------------
__global__ __launch_bounds__(256) void attn_mfma(
    const bf16_t* __restrict__ q, const bf16_t* __restrict__ kt,
    const bf16_t* __restrict__ vt, bf16_t* __restrict__ aot)
{
  const int p0 = blockIdx.x * 128;
  const int h  = blockIdx.y;
  const int b  = blockIdx.z;

  __shared__ __align__(16) char smem[51200];
  bf16_t (*Pt)[72] = (bf16_t(*)[72])(smem + 32768);  // [q 128][l]
  float  (*Os)[68] = (float (*)[68])(smem);          // epilogue reuse

  const int tid  = threadIdx.x;
  const int w    = tid >> 6;
  const int lane = tid & 63;
  const int l15  = lane & 15;
  const int g    = lane >> 4;
  const int lrow = lane >> 3;   // 0..7
  const int j    = lane & 7;

  const bf16_t* qb = q  + (size_t)(b * DIMX + h * DHEAD) * HW;
  const bf16_t* kb = kt + ((size_t)(b * NHEAD + h) * LKV) * DHEAD;
  const bf16_t* vb = vt + (size_t)(b * DIMX + h * DHEAD) * LKV;

  // staging pointers (pre-swizzled source column)
  const bf16_t* gK = kb + (size_t)(w * 16 + lrow) * DHEAD + (j ^ lrow) * 8;
  const bf16_t* gV = vb + (size_t)(w * 16 + lrow) * LKV + (j ^ lrow) * 8;

  // Q fragments (dual-use layout), pre-scaled by 0.125*log2(e)
  const float QSCL = 0.18033688011112042f;
  bf16x8 qf[2][2];
#pragma unroll
  for (int rs = 0; rs < 2; ++rs) {
    const int p = p0 + w * 32 + rs * 16 + l15;
    const bool valid = p < HW;
#pragma unroll
    for (int c2 = 0; c2 < 2; ++c2)
#pragma unroll
      for (int i = 0; i < 8; ++i) {
        const int d = c2 * 32 + g * 8 + i;
        qf[rs][c2][i] = valid ? (bf16_t)((float)qb[(size_t)d * HW + p] * QSCL) : (bf16_t)0.f;
      }
  }
  bf16x8 ones;
#pragma unroll
  for (int i = 0; i < 8; ++i) ones[i] = (bf16_t)1.0f;

  f32x4 acc[2][4];   // O^T: acc[rs][n][r] = O[d=n*16+g*4+r][q=rs*16+l15]
  f32x4 lacc[2];     // ones-MFMA row (all 4 regs identical) = sum_l P[l][q]
#pragma unroll
  for (int rs = 0; rs < 2; ++rs) {
    lacc[rs][0]=0.f; lacc[rs][1]=0.f; lacc[rs][2]=0.f; lacc[rs][3]=0.f;
#pragma unroll
    for (int n = 0; n < 4; ++n) { acc[rs][n][0]=0.f; acc[rs][n][1]=0.f; acc[rs][n][2]=0.f; acc[rs][n][3]=0.f; }
  }

  // prologue: stage tile 0 into buf0
  gload16(gK,                    smem + w * 2048);
  gload16(gK + (size_t)8*DHEAD,  smem + w * 2048 + 1024);
  gload16(gV,                    smem + 8192 + w * 2048);
  gload16(gV + (size_t)8*LKV,    smem + 8192 + w * 2048 + 1024);

  for (int t = 0; t < 13; ++t) {
    const int l0  = t * 64;
    const int buf = (t & 1) * 16384;
    __syncthreads();   // drains stage(t) (issued one phase ago); syncs LDS reuse
    if (t < 12) {
      const int l1 = l0 + 64;
      const int nb = ((t + 1) & 1) * 16384;
      gload16(gK + (size_t)l1 * DHEAD,       smem + nb + w * 2048);
      gload16(gK + (size_t)(l1 + 8) * DHEAD, smem + nb + w * 2048 + 1024);
      gload16(gV + l1,                       smem + nb + 8192 + w * 2048);
      gload16(gV + (size_t)8 * LKV + l1,     smem + nb + 8192 + w * 2048 + 1024);
    }

    // QK^T swapped: s[rs][n] = S^T rows l=l0+n*16+g*4+r, col q=rs*16+l15
    f32x4 s[2][4];
    __builtin_amdgcn_s_setprio(1);
#pragma unroll
    for (int n = 0; n < 4; ++n) {
      const int row = n * 16 + l15;
      const int cx0 = (g * 16) ^ ((l15 & 7) << 4);
      const int cx1 = (64 + g * 16) ^ ((l15 & 7) << 4);
      const bf16x8 k0 = *(const bf16x8*)(smem + buf + row * 128 + cx0);
      const bf16x8 k1 = *(const bf16x8*)(smem + buf + row * 128 + cx1);
#pragma unroll
      for (int rs = 0; rs < 2; ++rs) {
        f32x4 z; z[0]=0.f; z[1]=0.f; z[2]=0.f; z[3]=0.f;
        z = mfma16(k0, qf[rs][0], z);
        z = mfma16(k1, qf[rs][1], z);
        s[rs][n] = z;
      }
    }
    __builtin_amdgcn_s_setprio(0);
    if (l0 + 64 > LKV) {
#pragma unroll
      for (int n = 0; n < 4; ++n)
#pragma unroll
        for (int r = 0; r < 4; ++r)
          if (l0 + n * 16 + g * 4 + r >= LKV) {
#pragma unroll
            for (int rs = 0; rs < 2; ++rs) s[rs][n][r] = -1e30f;
          }
    }

    // P = exp2(s); packed b64 writes to Pt[q][l] (wave-local)
#pragma unroll
    for (int rs = 0; rs < 2; ++rs)
#pragma unroll
      for (int n = 0; n < 4; ++n) {
        bf16x4 pk;
#pragma unroll
        for (int r = 0; r < 4; ++r) pk[r] = (bf16_t)exp2f(s[rs][n][r]);
        *(bf16x4*)&Pt[w * 32 + rs * 16 + l15][n * 16 + g * 4] = pk;
      }

    // PV + lsum: acc = mfma(V^T, P^T); lacc = mfma(ones, P^T)
    __builtin_amdgcn_s_setprio(1);
#pragma unroll
    for (int c2 = 0; c2 < 2; ++c2) {
      bf16x8 vf[4];
#pragma unroll
      for (int n = 0; n < 4; ++n) {
        const int row = n * 16 + l15;
        const int cx = (c2 * 64 + g * 16) ^ ((l15 & 7) << 4);
        vf[n] = *(const bf16x8*)(smem + 8192 + buf + row * 128 + cx);
      }
#pragma unroll
      for (int rs = 0; rs < 2; ++rs) {
        const bf16x8 pf = *(const bf16x8*)&Pt[w * 32 + rs * 16 + l15][c2 * 32 + g * 8];
        lacc[rs] = mfma16(ones, pf, lacc[rs]);
#pragma unroll
        for (int n = 0; n < 4; ++n)
          acc[rs][n] = mfma16(vf[n], pf, acc[rs][n]);
      }
    }
    __builtin_amdgcn_s_setprio(0);
  }
  __syncthreads();   // all compute done before Os overlays K/V buffers

  // epilogue: normalize (lsum directly in lacc), packed Os writes
#pragma unroll
  for (int rs = 0; rs < 2; ++rs) {
    const float inv = 1.f / lacc[rs][0];
#pragma unroll
    for (int n = 0; n < 4; ++n) {
      f32x4 o4;
#pragma unroll
      for (int r = 0; r < 4; ++r) o4[r] = acc[rs][n][r] * inv;
      *(f32x4*)&Os[w * 32 + rs * 16 + l15][n * 16 + g * 4] = o4;
    }
  }
  __syncthreads();
  {
    const int pr = tid >> 1, c0 = (tid & 1) * 32;
    const int p = p0 + pr;
    if (p < HW) {
      bf16_t* dst = aot + ((size_t)b * HW + p) * DIMX + h * DHEAD + c0;
#pragma unroll
      for (int jj = 0; jj < 4; ++jj) {
        bf16x8 o8;
#pragma unroll
        for (int k = 0; k < 8; ++k) o8[k] = (bf16_t)Os[pr][c0 + jj * 8 + k];
        *(bf16x8*)(dst + jj * 8) = o8;
      }
    }
  }
}

// ---------------------------------------------------------------------------
extern "C" void kernel_launch(void* const* d_in, const int* in_sizes, int n_in,
                              void* d_out, int out_size, void* d_ws, size_t ws_size,
                              hipStream_t stream) {
  const float* x       = (const float*)d_in[0];
  const float* q_w     = (const float*)d_in[1];
  const float* kv_w    = (const float*)d_in[2];
  const float* proj_w  = (const float*)d_in[3];
  const float* proj_b  = (const float*)d_in[4];
  const float* dw_w    = (const float*)d_in[5];
  const float* dw_b    = (const float*)d_in[6];
  const float* bn_w    = (const float*)d_in[7];
  const float* bn_b    = (const float*)d_in[8];
  const float* bn_mean = (const float*)d_in[9];
  const float* bn_var  = (const float*)d_in[10];
  const float* pw_w    = (const float*)d_in[11];
  float* out = (float*)d_out;

  // workspace (bytes), total ~64 MB
  char* ws = (char*)d_ws;
  bf16_t* qbufb = (bf16_t*)(ws);                      // 19,267,584 (8,384,3136) bf16
  float*  offb  = (float*)(ws + 19267584);            //  9,633,792 (24,128,784) f32
  float*  gxy   = (float*)(ws + 28901376);            //    150,528
  float*  modb  = (float*)(ws + 29051904);            //     75,264
  bf16_t* ktb   = (bf16_t*)(ws + 29127168);           //  4,816,896 (8,6,784,64) bf16
  bf16_t* vtb   = (bf16_t*)(ws + 33944064);           //  4,816,896 (8,384,784) bf16
  bf16_t* xsb   = (bf16_t*)(ws + 38760960);           //  4,816,896 (24,128,784) bf16
  bf16_t* xt    = (bf16_t*)(ws + 43577856);           // 19,267,584 (8,3136,384) bf16
  bf16_t* aot   = xt;                                 // overlay: xt dead after q-proj
  bf16_t* wbf   = (bf16_t*)(ws + 62845440);           //  1,179,648 weights bf16
  bf16_t* q_wb  = wbf;
  bf16_t* kv_wb = wbf + 147456;
  bf16_t* pj_wb = wbf + 442368;

  const dim3 blk(256);
  // 0. converts
  xt_cvt<<<dim3(49, 6, 8), blk, 0, stream>>>(x, xt);
  cvt_w3<<<dim3(576), blk, 0, stream>>>(q_w, kv_w, proj_w, wbf);
  // 1. q projection (fast path, bf16 out)
  gemm_qo<false, true><<<dim3(49, 6, 8), blk, 0, stream>>>(q_wb, xt, nullptr, qbufb, 384, 3136, 384);
  // 2. depthwise conv + BN + GELU (bf16 in)
  dw_bn_gelu<<<dim3(3072), blk, 0, stream>>>(qbufb, dw_w, dw_b, bn_w, bn_b, bn_mean, bn_var, offb);
  // 3. pointwise -> offsets + (double-sigmoid) modulation -> coords
  om_grid<<<dim3(4, 24), blk, 0, stream>>>(offb, pw_w, gxy, modb);
  // 4. bilinear sample * modulation -> bf16 (c-major)
  sample_mod<<<dim3(3072), blk, 0, stream>>>(x, gxy, modb, xsb);
  // 5. kv projection -> K transposed [b,h,l,d] + V [b,c,l]
  gemm_kv<<<dim3(13, 12, 8), blk, 0, stream>>>(kv_wb, xsb, ktb, vtb, 384, 784, 768);
  // 6. attention (swapped QK^T, dbuf, ones-MFMA lsum) -> aot (b,p,c) bf16
  attn_mfma<<<dim3(25, 6, 8), blk, 0, stream>>>(qbufb, ktb, vtb, aot);
  // 7. out projection (+bias, fast path) -> d_out fp32
  gemm_qo<true, false><<<dim3(49, 6, 8), blk, 0, stream>>>(pj_wb, aot, proj_b, out, 384, 3136, 384);
}